// Round 2
// baseline (1300.005 us; speedup 1.0000x reference)
//
#include <hip/hip_runtime.h>
#include <stdint.h>

// ============================================================================
// DSVABlockLarge — round 2: dtype-robust correctness baseline.
//  * Runtime detection of float dtype (bf16 vs f32) from voxel_tokens content;
//    all float inputs canonicalized to bf16 in ws; output store branches on
//    detected dtype. Mask encoding (int32/f32/bf16/byte) detected separately.
//  * KNN matches jax.lax.top_k exactly: integer d2 ranking, (d2,index)
//    tie-break; empty keys absorbed into exactly 1e9 -> never selected.
//  * f32 accumulation everywhere; ws usage ~44.2 MB.
// ============================================================================

using u16 = unsigned short;
using u32 = unsigned int;
using u64 = unsigned long long;

#define DEV static __device__ __forceinline__

constexpr int cV = 4096, cD = 192;
constexpr int cE = 384;
constexpr int cKN = 16, cTK = 8;
constexpr int cM = 2 * cV;   // 8192 rows (B*V)
constexpr int c3E = 1152;

DEV float bf2f(u16 v) { return __uint_as_float(((u32)v) << 16); }
DEV float bflo(u32 v) { return __uint_as_float(v << 16); }
DEV float bfhi(u32 v) { return __uint_as_float(v & 0xFFFF0000u); }
DEV u16 f2bf(float f) {
  u32 u = __float_as_uint(f);
  u = (u + 0x7FFFu + ((u >> 16) & 1u)) >> 16;
  return (u16)u;
}
DEV int mget(const void* mp, int flag, int i) {
  if (flag == 0) return ((const int*)mp)[i] != 0;
  if (flag == 1) return ((const float*)mp)[i] != 0.0f;
  if (flag == 2) return ((const u16*)mp)[i] != 0;
  return ((const unsigned char*)mp)[i] != 0;
}
DEV float gelu_tanh(float x) {  // jax.nn.gelu approximate=True
  float t = tanhf(0.7978845608028654f * (x + 0.044715f * x * x * x));
  return 0.5f * x * (1.0f + t);
}
DEV u32 f2ord(float f) {
  u32 u = __float_as_uint(f);
  return (u & 0x80000000u) ? ~u : (u | 0x80000000u);
}
DEV float ord2f(u32 o) {
  u32 bits = (o & 0x80000000u) ? (o & 0x7FFFFFFFu) : ~o;
  return __uint_as_float(bits);
}
DEV int bf_plausible(u32 h) {
  if (h == 0u || h == 0x8000u) return 1;
  u32 e = (h >> 7) & 0xFFu;
  return (e >= 100u && e <= 140u) ? 1 : 0;  // |x| in ~[2^-27, 2^13]
}

// ---------------------------------------------------------------------------
// Float dtype sniffer: flag[1] = 1 if voxel_tokens is bf16, 0 if f32.
// bf16 data: both u16 halves of each dword are plausible bf16 (~100%).
// f32 data: low half is mantissa bits -> plausible only ~16% of the time.
__global__ void detect_dtype_kernel(const u32* __restrict__ tok, int* __restrict__ flag) {
  __shared__ int cnt;
  if (threadIdx.x == 0) cnt = 0;
  __syncthreads();
  int c = 0;
  for (int i = threadIdx.x; i < 4096; i += 256) {
    u32 d = tok[i];
    c += bf_plausible(d & 0xFFFFu) & bf_plausible(d >> 16);
  }
  atomicAdd(&cnt, c);
  __syncthreads();
  if (threadIdx.x == 0) flag[1] = (cnt > 3400) ? 1 : 0;
}

// Mask dtype classifier: flag[0] in {0:int32, 1:f32, 2:bf16, 3:byte}.
__global__ void detect_mask_kernel(const u32* __restrict__ m, int* __restrict__ flag) {
  __shared__ int sa, sb, sc;
  if (threadIdx.x == 0) { sa = 0; sb = 0; sc = 0; }
  __syncthreads();
  int a = 0, b = 0, c = 0;
  for (int i = threadIdx.x; i < 2048; i += 256) {
    u32 d = m[i];
    if (!(d == 0u || d == 1u)) a = 1;
    if (!(d == 0u || d == 0x3F800000u)) b = 1;
    if (!(d == 0u || d == 0x00003F80u || d == 0x3F800000u || d == 0x3F803F80u)) c = 1;
  }
  if (a) atomicOr(&sa, 1);
  if (b) atomicOr(&sb, 1);
  if (c) atomicOr(&sc, 1);
  __syncthreads();
  if (threadIdx.x == 0) flag[0] = (sa == 0) ? 0 : ((sb == 0) ? 1 : ((sc == 0) ? 2 : 3));
}

// Canonicalize all float tensors to bf16 (copy if already bf16).
struct ConvArgs {
  const void* src[17];
  u16* dst[17];
  int n[17];
};
__global__ __launch_bounds__(256) void convert_all_kernel(ConvArgs a, const int* __restrict__ flag) {
  const int t = blockIdx.y;
  const int dt = flag[1];
  const int n = a.n[t];
  u16* d = a.dst[t];
  if (dt) {
    const u16* s = (const u16*)a.src[t];
    for (int i = blockIdx.x * 256 + threadIdx.x; i < n; i += gridDim.x * 256) d[i] = s[i];
  } else {
    const float* s = (const float*)a.src[t];
    for (int i = blockIdx.x * 256 + threadIdx.x; i < n; i += gridDim.x * 256) d[i] = f2bf(s[i]);
  }
}

// ---------------------------------------------------------------------------
// Exact KNN: one wave per (b,v). Integer d2 histogram (0..675), wave-scan for
// the 16th-smallest threshold T, collect {d2<T} unordered + smallest-index
// fills from bucket T. Set-equality with jax top_k is exact.
__global__ __launch_bounds__(64) void knn_kernel(const void* __restrict__ mask,
                                                 const int* __restrict__ flag,
                                                 int* __restrict__ knn_out) {
  const int bq = blockIdx.x;
  const int b = bq >> 12;
  const int v = bq & 4095;
  const int lane = threadIdx.x;
  const int fl = flag[0];
  __shared__ int hist[676];
  __shared__ int out16[cKN];
  __shared__ int listT[256];
  __shared__ int cntA, cntT, sT, sBelow;
  for (int i = lane; i < 676; i += 64) hist[i] = 0;
  if (lane < cKN) out16[lane] = 0;
  if (lane == 0) { cntA = 0; cntT = 0; sT = 676; sBelow = 0; }
  __syncthreads();
  const int iv = v >> 8, jv = (v >> 4) & 15, kv = v & 15;
  const int mbase = b * cV;
  for (int t = 0; t < 64; ++t) {
    int u = t * 64 + lane;
    if (mget(mask, fl, mbase + u)) {
      int di = iv - (u >> 8), dj = jv - ((u >> 4) & 15), dk = kv - (u & 15);
      atomicAdd(&hist[di * di + dj * dj + dk * dk], 1);
    }
  }
  __syncthreads();
  int cnt = 0;
  #pragma unroll
  for (int t = 0; t < 11; ++t) { int bk = lane * 11 + t; if (bk < 676) cnt += hist[bk]; }
  int incl = cnt;
  for (int off = 1; off < 64; off <<= 1) { int nv = __shfl_up(incl, off); if (lane >= off) incl += nv; }
  int excl = incl - cnt;
  if (excl < cKN && incl >= cKN) {
    int cum = excl;
    for (int t = 0; t < 11; ++t) {
      int bk = lane * 11 + t;
      if (bk < 676) {
        int hh = hist[bk];
        if (hh > 0 && cum + hh >= cKN) { sT = bk; sBelow = cum; break; }
        cum += hh;
      }
    }
  }
  __syncthreads();
  const int T = sT, below = sBelow;
  for (int t = 0; t < 64; ++t) {
    int u = t * 64 + lane;
    if (mget(mask, fl, mbase + u)) {
      int di = iv - (u >> 8), dj = jv - ((u >> 4) & 15), dk = kv - (u & 15);
      int d2 = di * di + dj * dj + dk * dk;
      if (d2 < T) { int p = atomicAdd(&cntA, 1); if (p < cKN) out16[p] = u; }
      else if (d2 == T) { int p = atomicAdd(&cntT, 1); if (p < 256) listT[p] = u; }
    }
  }
  __syncthreads();
  if (lane == 0) {
    int need = cKN - below;
    int nT = cntT < 256 ? cntT : 256;
    if (need > nT) need = nT;
    for (int r = 0; r < need; ++r) {
      int bi = 0, bu = 0x7FFFFFFF;
      for (int i = 0; i < nT; ++i) { int x = listT[i]; if (x < bu) { bu = x; bi = i; } }
      out16[below + r] = bu;
      listT[bi] = 0x7FFFFFFF;
    }
  }
  __syncthreads();
  if (lane < cKN) knn_out[bq * cKN + lane] = out16[lane];
}

// ---------------------------------------------------------------------------
// Generic row-tiled GEMM: C[M,N] = A[M,K] @ W[K,N] (+bias, fused epilogue).
// 256 threads = 16 rows x 16 col-threads, 8 consecutive cols per thread/chunk.
enum { EPI_NONE = 0, EPI_LN = 1, EPI_MASK = 2, EPI_RES_TOK = 3, EPI_GELU = 4, EPI_RES_XM = 5 };

template <int EPI, typename AT>
__global__ __launch_bounds__(256) void gemm_kernel(
    const AT* __restrict__ A, const u16* __restrict__ W, const u16* __restrict__ bias,
    void* __restrict__ outv, int K, int N,
    const u16* __restrict__ g, const u16* __restrict__ bt,
    const void* __restrict__ mask, const int* __restrict__ flag,
    const u16* __restrict__ tok, const float* __restrict__ xm) {
  extern __shared__ float smem[];
  float* Af = smem;                // 16*K f32
  float* lnb = smem + 16 * K;      // 16*N f32 (EPI_LN only)
  const int tid = threadIdx.x;
  const int ty = tid >> 4, tx = tid & 15;
  const int row0 = blockIdx.x * 16;
  for (int r = 0; r < 16; ++r) {
    const size_t abase = (size_t)(row0 + r) * K;
    for (int c = tid; c < K; c += 256) {
      float av;
      if constexpr (sizeof(AT) == 2) av = bf2f(((const u16*)A)[abase + c]);
      else av = ((const float*)A)[abase + c];
      Af[r * K + c] = av;
    }
  }
  __syncthreads();
  const int row = row0 + ty;
  u16* out16p = (u16*)outv;
  float* out32p = (float*)outv;
  for (int cb = 0; cb < N; cb += 128) {
    const int c0 = cb + tx * 8;
    if (c0 >= N) continue;
    float a0 = 0, a1 = 0, a2 = 0, a3 = 0, a4 = 0, a5 = 0, a6 = 0, a7 = 0;
    const u16* wp = W + c0;
    const float* ap = Af + ty * K;
    for (int d = 0; d < K; ++d) {
      float a = ap[d];
      uint4 wv = *(const uint4*)wp;
      wp += N;
      a0 += a * bflo(wv.x); a1 += a * bfhi(wv.x);
      a2 += a * bflo(wv.y); a3 += a * bfhi(wv.y);
      a4 += a * bflo(wv.z); a5 += a * bfhi(wv.z);
      a6 += a * bflo(wv.w); a7 += a * bfhi(wv.w);
    }
    float res[8] = {a0, a1, a2, a3, a4, a5, a6, a7};
    #pragma unroll
    for (int j = 0; j < 8; ++j) res[j] += bf2f(bias[c0 + j]);
    const size_t obase = (size_t)row * N + c0;
    if constexpr (EPI == EPI_NONE) {
      #pragma unroll
      for (int j = 0; j < 8; ++j) out16p[obase + j] = f2bf(res[j]);
    } else if constexpr (EPI == EPI_LN) {
      #pragma unroll
      for (int j = 0; j < 8; ++j) lnb[ty * N + c0 + j] = res[j];
    } else if constexpr (EPI == EPI_MASK) {
      float fm = mget(mask, flag[0], row) ? 1.0f : 0.0f;
      #pragma unroll
      for (int j = 0; j < 8; ++j) out16p[obase + j] = f2bf(res[j] * fm);
    } else if constexpr (EPI == EPI_RES_TOK) {
      #pragma unroll
      for (int j = 0; j < 8; ++j) out32p[obase + j] = res[j] * 0.5f + bf2f(tok[obase + j]);
    } else if constexpr (EPI == EPI_GELU) {
      #pragma unroll
      for (int j = 0; j < 8; ++j) out16p[obase + j] = f2bf(gelu_tanh(res[j]));
    } else if constexpr (EPI == EPI_RES_XM) {
      const int dtf = flag[1];
      #pragma unroll
      for (int j = 0; j < 8; ++j) {
        float v = res[j] * 0.5f + xm[obase + j];
        if (dtf) out16p[obase + j] = f2bf(v);
        else out32p[obase + j] = v;
      }
    }
  }
  if constexpr (EPI == EPI_LN) {
    __syncthreads();
    float s = 0, sq = 0;
    for (int c = tx; c < N; c += 16) { float x = lnb[ty * N + c]; s += x; sq += x * x; }
    #pragma unroll
    for (int mdist = 1; mdist < 16; mdist <<= 1) { s += __shfl_xor(s, mdist); sq += __shfl_xor(sq, mdist); }
    float mean = s / N;
    float var = sq / N - mean * mean;
    float rstd = rsqrtf(var + 1e-5f);
    const size_t obase = (size_t)row * N;
    for (int c = tx; c < N; c += 16) {
      float x = (lnb[ty * N + c] - mean) * rstd * bf2f(g[c]) + bf2f(bt[c]);
      out16p[obase + c] = f2bf(x);
    }
  }
}

// ---------------------------------------------------------------------------
// Gathered sparse attention: one wave per (b,v). K/V of 16 neighbors staged in
// LDS; scores f32; per-head top-8 with (value, lower-index) tie-break; softmax;
// weighted V sum. All knn entries are valid (>=16 non-empty always).
__global__ __launch_bounds__(64) void attn_kernel(const u16* __restrict__ qkv,
                                                  const int* __restrict__ knn,
                                                  u16* __restrict__ o_out) {
  const int bq = blockIdx.x;
  const int lane = threadIdx.x;
  const int b = bq >> 12;
  __shared__ uint4 qb4[48];
  __shared__ uint4 kb4[16][48];
  __shared__ uint4 vb4[16][48];
  __shared__ int nb[16];
  __shared__ u64 sck[8][16];
  __shared__ float w[8][8];
  __shared__ int seln[8][8];
  if (lane < 16) nb[lane] = knn[bq * cKN + lane];
  if (lane < 48) qb4[lane] = *((const uint4*)(qkv + (size_t)bq * c3E) + lane);
  __syncthreads();
  for (int n = 0; n < 16; ++n) {
    const size_t rbase = ((size_t)(b * cV + nb[n])) * c3E;
    if (lane < 48) {
      kb4[n][lane] = *((const uint4*)(qkv + rbase + cE) + lane);
      vb4[n][lane] = *((const uint4*)(qkv + rbase + 2 * cE) + lane);
    }
  }
  __syncthreads();
  {
    const int h = lane >> 3;
    const int n0 = (lane & 7) * 2;
    const u32* qu = (const u32*)qb4 + h * 24;
    const u32* k0 = (const u32*)kb4 + n0 * 192 + h * 24;
    const u32* k1 = (const u32*)kb4 + (n0 + 1) * 192 + h * 24;
    float s0 = 0.f, s1 = 0.f;
    #pragma unroll
    for (int j = 0; j < 24; ++j) {
      u32 q = qu[j];
      float ql = bflo(q), qh = bfhi(q);
      u32 ka = k0[j]; s0 += ql * bflo(ka) + qh * bfhi(ka);
      u32 kb = k1[j]; s1 += ql * bflo(kb) + qh * bfhi(kb);
    }
    const float inv = 0.14433756729740643f;  // 1/sqrt(48)
    s0 *= inv; s1 *= inv;
    sck[h][n0]     = (((u64)f2ord(s0)) << 4) | (u64)(15 - n0);
    sck[h][n0 + 1] = (((u64)f2ord(s1)) << 4) | (u64)(15 - (n0 + 1));
  }
  __syncthreads();
  if ((lane & 7) == 0) {
    const int h = lane >> 3;
    float m0 = 0.f, Z = 0.f;
    #pragma unroll
    for (int r = 0; r < cTK; ++r) {
      u64 best = 0; int bn = 0;
      for (int n = 0; n < 16; ++n) { u64 kk = sck[h][n]; if (kk > best) { best = kk; bn = n; } }
      sck[h][bn] = 0;
      float sv = ord2f((u32)(best >> 4));
      seln[h][r] = 15 - (int)(best & 15ull);
      if (r == 0) m0 = sv;
      float e = expf(sv - m0);
      w[h][r] = e;
      Z += e;
    }
    float iZ = 1.0f / Z;
    #pragma unroll
    for (int r = 0; r < cTK; ++r) w[h][r] *= iZ;
  }
  __syncthreads();
  const u16* vb = (const u16*)vb4;
  #pragma unroll
  for (int rep = 0; rep < 6; ++rep) {
    int e = lane + rep * 64;
    int h = e / 48;
    float acc = 0.f;
    #pragma unroll
    for (int t = 0; t < cTK; ++t) acc += w[h][t] * bf2f(vb[seln[h][t] * cE + e]);
    o_out[(size_t)bq * cE + e] = f2bf(acc);
  }
}

// ---------------------------------------------------------------------------
extern "C" void kernel_launch(void* const* d_in, const int* in_sizes, int n_in,
                              void* d_out, int out_size, void* d_ws, size_t ws_size,
                              hipStream_t stream) {
  if (n_in < 18) return;
  const void* mask = d_in[1];

  char* ws = (char*)d_ws;
  size_t off = 0;
  auto alloc = [&](size_t bytes) { size_t o = off; off += (bytes + 255) & ~(size_t)255; return o; };
  int* flag  = (int*)(ws + alloc(256));
  int* knn   = (int*)(ws + alloc((size_t)cM * cKN * 4));
  float* XM  = (float*)(ws + alloc((size_t)cM * cD * 4));   // x after first residual (f32)
  u16* S1    = (u16*)(ws + alloc((size_t)cM * cE * 2));     // x1 / xe
  u16* S2    = (u16*)(ws + alloc((size_t)cM * cE * 2));     // attn o / f2
  u16* QB    = (u16*)(ws + alloc((size_t)cM * c3E * 2));    // qkv; later HB + S3
  u16* HB    = QB;                                          // h (B,V,2E) = 12.58MB
  u16* S3    = QB + (size_t)cM * 2 * cE;                    // masked Wo out (6.29MB)
  // canonical bf16 copies of float inputs
  static const int tsz[17] = {cM * cD,            // tok
      cD * cE, cE, cE, cE,                        // We be g1 bt1
      cE * c3E, c3E, cE * cE, cE,                 // Wqkv bqkv Wo bo
      cE * cD, cD, cE, cE,                        // Wc bc g2 bt2
      cE * 2 * cE, 2 * cE, 2 * cE * cE, cE};     // W1 b1 W2 b2
  u16* cp[17];
  {
    size_t total = 0;
    for (int i = 0; i < 17; ++i) total += (size_t)tsz[i];
    u16* base = (u16*)(ws + alloc(total * 2));
    size_t o2 = 0;
    for (int i = 0; i < 17; ++i) { cp[i] = base + o2; o2 += (size_t)tsz[i]; }
  }
  const u16 *tokc = cp[0], *We = cp[1], *be = cp[2], *g1 = cp[3], *bt1 = cp[4],
            *Wqkv = cp[5], *bqkv = cp[6], *Wo = cp[7], *bo = cp[8],
            *Wc = cp[9], *bc = cp[10], *g2 = cp[11], *bt2 = cp[12],
            *W1 = cp[13], *b1 = cp[14], *W2 = cp[15], *b2 = cp[16];
  (void)ws_size; (void)in_sizes; (void)out_size;

  detect_dtype_kernel<<<1, 256, 0, stream>>>((const u32*)d_in[0], flag);
  detect_mask_kernel<<<1, 256, 0, stream>>>((const u32*)mask, flag);

  ConvArgs ca;
  // source input indices: tok=0, then weights at d_in[2..17]
  ca.src[0] = d_in[0]; ca.dst[0] = cp[0]; ca.n[0] = tsz[0];
  for (int i = 1; i < 17; ++i) { ca.src[i] = d_in[i + 1]; ca.dst[i] = cp[i]; ca.n[i] = tsz[i]; }
  convert_all_kernel<<<dim3(512, 17), 256, 0, stream>>>(ca, flag);

  knn_kernel<<<cM, 64, 0, stream>>>(mask, flag, knn);

  // G1: x1 = LN(tok @ We + be; g1,bt1)
  gemm_kernel<EPI_LN, u16><<<cM / 16, 256, (16 * cD + 16 * cE) * 4, stream>>>(
      tokc, We, be, S1, cD, cE, g1, bt1, nullptr, flag, nullptr, nullptr);
  // G2: qkv = x1 @ Wqkv + bqkv
  gemm_kernel<EPI_NONE, u16><<<cM / 16, 256, 16 * cE * 4, stream>>>(
      S1, Wqkv, bqkv, QB, cE, c3E, nullptr, nullptr, nullptr, flag, nullptr, nullptr);
  // G3: gathered attention
  attn_kernel<<<cM, 64, 0, stream>>>(QB, knn, S2);
  // G4: S3 = (o @ Wo + bo) * fmask
  gemm_kernel<EPI_MASK, u16><<<cM / 16, 256, 16 * cE * 4, stream>>>(
      S2, Wo, bo, S3, cE, cE, nullptr, nullptr, mask, flag, nullptr, nullptr);
  // G5: XM = (S3 @ Wc + bc)*0.5 + tok   (f32)
  gemm_kernel<EPI_RES_TOK, u16><<<cM / 16, 256, 16 * cE * 4, stream>>>(
      S3, Wc, bc, XM, cE, cD, nullptr, nullptr, nullptr, flag, tokc, nullptr);
  // G6: xe = LN(XM @ We + be; g2,bt2)
  gemm_kernel<EPI_LN, float><<<cM / 16, 256, (16 * cD + 16 * cE) * 4, stream>>>(
      XM, We, be, S1, cD, cE, g2, bt2, nullptr, flag, nullptr, nullptr);
  // G7: h = gelu(xe @ W1 + b1)
  gemm_kernel<EPI_GELU, u16><<<cM / 16, 256, 16 * cE * 4, stream>>>(
      S1, W1, b1, HB, cE, 2 * cE, nullptr, nullptr, nullptr, flag, nullptr, nullptr);
  // G8: f2 = h @ W2 + b2
  gemm_kernel<EPI_NONE, u16><<<cM / 16, 256, 16 * 2 * cE * 4, stream>>>(
      HB, W2, b2, S2, 2 * cE, cE, nullptr, nullptr, nullptr, flag, nullptr, nullptr);
  // G9: out = (f2 @ Wc + bc)*0.5 + XM   (dtype per flag[1])
  gemm_kernel<EPI_RES_XM, u16><<<cM / 16, 256, 16 * cE * 4, stream>>>(
      S2, Wc, bc, d_out, cE, cD, nullptr, nullptr, nullptr, flag, nullptr, XM);
}

// Round 3
// 291.473 us; speedup vs baseline: 4.4601x; 4.4601x over previous
//
#include <hip/hip_runtime.h>
#include <stdint.h>

// ============================================================================
// DSVABlockLarge — round 3: MFMA GEMMs (m97 structure), fused epilogues.
//  * All 8 GEMMs -> v_mfma_f32_16x16x32_bf16, 128x128 tile, BK=64, 4 waves,
//    global_load_lds width-16 staging, B^T operand (weights pre-transposed).
//  * LN as separate row-per-wave kernel (can't fuse across col-blocks).
//  * dtype detection (bf16 vs f32) + mask encoding detection: unchanged.
//  * KNN / attn kernels: unchanged from passing round 2.
// ============================================================================

using u16 = unsigned short;
using u32 = unsigned int;
using u64 = unsigned long long;

typedef short short8 __attribute__((ext_vector_type(8)));
typedef float f32x4 __attribute__((ext_vector_type(4)));

#define DEV static __device__ __forceinline__

constexpr int cV = 4096, cD = 192;
constexpr int cE = 384;
constexpr int cKN = 16, cTK = 8;
constexpr int cM = 2 * cV;   // 8192 rows (B*V)
constexpr int c3E = 1152;

DEV float bf2f(u16 v) { return __uint_as_float(((u32)v) << 16); }
DEV float bflo(u32 v) { return __uint_as_float(v << 16); }
DEV float bfhi(u32 v) { return __uint_as_float(v & 0xFFFF0000u); }
DEV u16 f2bf(float f) {
  u32 u = __float_as_uint(f);
  u = (u + 0x7FFFu + ((u >> 16) & 1u)) >> 16;
  return (u16)u;
}
DEV int mget(const void* mp, int flag, int i) {
  if (flag == 0) return ((const int*)mp)[i] != 0;
  if (flag == 1) return ((const float*)mp)[i] != 0.0f;
  if (flag == 2) return ((const u16*)mp)[i] != 0;
  return ((const unsigned char*)mp)[i] != 0;
}
DEV float gelu_tanh(float x) {
  float t = tanhf(0.7978845608028654f * (x + 0.044715f * x * x * x));
  return 0.5f * x * (1.0f + t);
}
DEV u32 f2ord(float f) {
  u32 u = __float_as_uint(f);
  return (u & 0x80000000u) ? ~u : (u | 0x80000000u);
}
DEV float ord2f(u32 o) {
  u32 bits = (o & 0x80000000u) ? (o & 0x7FFFFFFFu) : ~o;
  return __uint_as_float(bits);
}
DEV int bf_plausible(u32 h) {
  if (h == 0u || h == 0x8000u) return 1;
  u32 e = (h >> 7) & 0xFFu;
  return (e >= 100u && e <= 140u) ? 1 : 0;
}

using as1p = const unsigned int __attribute__((address_space(1)))*;
using as3p = unsigned int __attribute__((address_space(3)))*;
DEV void gload16(const void* g, void* l) {
  __builtin_amdgcn_global_load_lds((as1p)g, (as3p)l, 16, 0, 0);
}
DEV f32x4 mfma16x16x32_bf16(short8 a, short8 b, f32x4 c) {
  asm volatile("v_mfma_f32_16x16x32_bf16 %0, %1, %2, %0" : "+v"(c) : "v"(a), "v"(b));
  return c;
}

// ---------------------------------------------------------------------------
__global__ void detect_dtype_kernel(const u32* __restrict__ tok, int* __restrict__ flag) {
  __shared__ int cnt;
  if (threadIdx.x == 0) cnt = 0;
  __syncthreads();
  int c = 0;
  for (int i = threadIdx.x; i < 4096; i += 256) {
    u32 d = tok[i];
    c += bf_plausible(d & 0xFFFFu) & bf_plausible(d >> 16);
  }
  atomicAdd(&cnt, c);
  __syncthreads();
  if (threadIdx.x == 0) flag[1] = (cnt > 3400) ? 1 : 0;
}

__global__ void detect_mask_kernel(const u32* __restrict__ m, int* __restrict__ flag) {
  __shared__ int sa, sb, sc;
  if (threadIdx.x == 0) { sa = 0; sb = 0; sc = 0; }
  __syncthreads();
  int a = 0, b = 0, c = 0;
  for (int i = threadIdx.x; i < 2048; i += 256) {
    u32 d = m[i];
    if (!(d == 0u || d == 1u)) a = 1;
    if (!(d == 0u || d == 0x3F800000u)) b = 1;
    if (!(d == 0u || d == 0x00003F80u || d == 0x3F800000u || d == 0x3F803F80u)) c = 1;
  }
  if (a) atomicOr(&sa, 1);
  if (b) atomicOr(&sb, 1);
  if (c) atomicOr(&sc, 1);
  __syncthreads();
  if (threadIdx.x == 0) flag[0] = (sa == 0) ? 0 : ((sb == 0) ? 1 : ((sc == 0) ? 2 : 3));
}

// Canonicalize tok + 10 bias/gain vectors to bf16.
struct ConvArgs {
  const void* src[11];
  u16* dst[11];
  int n[11];
};
__global__ __launch_bounds__(256) void convert_all_kernel(ConvArgs a, const int* __restrict__ flag) {
  const int t = blockIdx.y;
  const int dt = flag[1];
  const int n = a.n[t];
  u16* d = a.dst[t];
  if (dt) {
    const u16* s = (const u16*)a.src[t];
    for (int i = blockIdx.x * 256 + threadIdx.x; i < n; i += gridDim.x * 256) d[i] = s[i];
  } else {
    const float* s = (const float*)a.src[t];
    for (int i = blockIdx.x * 256 + threadIdx.x; i < n; i += gridDim.x * 256) d[i] = f2bf(s[i]);
  }
}

// Transpose 6 weight matrices [K][N] -> bf16 [N][K] (rows may be padded; pad
// rows left uninitialized, guarded at GEMM store).
struct TArgs {
  const void* src[6];
  u16* dst[6];
  int K[6];
  int N[6];
};
__global__ __launch_bounds__(256) void transpose_w_kernel(TArgs a, const int* __restrict__ flag) {
  const int t = blockIdx.y;
  const int K = a.K[t], N = a.N[t];
  const int total = K * N;
  const int dt = flag[1];
  u16* d = a.dst[t];
  for (int i = blockIdx.x * 256 + threadIdx.x; i < total; i += gridDim.x * 256) {
    int n = i / K, k = i - n * K;
    u16 vv;
    if (dt) vv = ((const u16*)a.src[t])[(size_t)k * N + n];
    else vv = f2bf(((const float*)a.src[t])[(size_t)k * N + n]);
    d[i] = vv;
  }
}

// ---------------------------------------------------------------------------
// Exact KNN (unchanged from round 2).
__global__ __launch_bounds__(64) void knn_kernel(const void* __restrict__ mask,
                                                 const int* __restrict__ flag,
                                                 int* __restrict__ knn_out) {
  const int bq = blockIdx.x;
  const int b = bq >> 12;
  const int v = bq & 4095;
  const int lane = threadIdx.x;
  const int fl = flag[0];
  __shared__ int hist[676];
  __shared__ int out16[cKN];
  __shared__ int listT[256];
  __shared__ int cntA, cntT, sT, sBelow;
  for (int i = lane; i < 676; i += 64) hist[i] = 0;
  if (lane < cKN) out16[lane] = 0;
  if (lane == 0) { cntA = 0; cntT = 0; sT = 676; sBelow = 0; }
  __syncthreads();
  const int iv = v >> 8, jv = (v >> 4) & 15, kv = v & 15;
  const int mbase = b * cV;
  for (int t = 0; t < 64; ++t) {
    int u = t * 64 + lane;
    if (mget(mask, fl, mbase + u)) {
      int di = iv - (u >> 8), dj = jv - ((u >> 4) & 15), dk = kv - (u & 15);
      atomicAdd(&hist[di * di + dj * dj + dk * dk], 1);
    }
  }
  __syncthreads();
  int cnt = 0;
  #pragma unroll
  for (int t = 0; t < 11; ++t) { int bk = lane * 11 + t; if (bk < 676) cnt += hist[bk]; }
  int incl = cnt;
  for (int off = 1; off < 64; off <<= 1) { int nv = __shfl_up(incl, off); if (lane >= off) incl += nv; }
  int excl = incl - cnt;
  if (excl < cKN && incl >= cKN) {
    int cum = excl;
    for (int t = 0; t < 11; ++t) {
      int bk = lane * 11 + t;
      if (bk < 676) {
        int hh = hist[bk];
        if (hh > 0 && cum + hh >= cKN) { sT = bk; sBelow = cum; break; }
        cum += hh;
      }
    }
  }
  __syncthreads();
  const int T = sT, below = sBelow;
  for (int t = 0; t < 64; ++t) {
    int u = t * 64 + lane;
    if (mget(mask, fl, mbase + u)) {
      int di = iv - (u >> 8), dj = jv - ((u >> 4) & 15), dk = kv - (u & 15);
      int d2 = di * di + dj * dj + dk * dk;
      if (d2 < T) { int p = atomicAdd(&cntA, 1); if (p < cKN) out16[p] = u; }
      else if (d2 == T) { int p = atomicAdd(&cntT, 1); if (p < 256) listT[p] = u; }
    }
  }
  __syncthreads();
  if (lane == 0) {
    int need = cKN - below;
    int nT = cntT < 256 ? cntT : 256;
    if (need > nT) need = nT;
    for (int r = 0; r < need; ++r) {
      int bi = 0, bu = 0x7FFFFFFF;
      for (int i = 0; i < nT; ++i) { int x = listT[i]; if (x < bu) { bu = x; bi = i; } }
      out16[below + r] = bu;
      listT[bi] = 0x7FFFFFFF;
    }
  }
  __syncthreads();
  if (lane < cKN) knn_out[bq * cKN + lane] = out16[lane];
}

// ---------------------------------------------------------------------------
// MFMA GEMM: C[8192,N] = A[8192,K](bf16) @ WT[N,K]^T (+bias, fused epilogue).
// 128x128 tile, BK=64, 4 waves each computing 64x64 via 4x4 16x16x32 frags.
enum { EPI_NONE = 0, EPI_MASK = 2, EPI_RES_TOK = 3, EPI_GELU = 4, EPI_RES_XM = 5 };

template <int EPI>
__global__ __launch_bounds__(256) void gemm_mfma(
    const u16* __restrict__ A, const u16* __restrict__ WT,
    const u16* __restrict__ bias, void* __restrict__ outv,
    int N, int K,
    const void* __restrict__ mask, const int* __restrict__ flag,
    const u16* __restrict__ tok, const float* __restrict__ xm,
    u16* __restrict__ xmb) {
  __shared__ alignas(16) u16 Alds[128 * 64];
  __shared__ alignas(16) u16 Blds[128 * 64];
  const int tid = threadIdx.x;
  const int lane = tid & 63;
  const int wid = tid >> 6;
  const int row0 = blockIdx.x * 128;
  const int col0 = blockIdx.y * 128;
  const int wr = wid >> 1, wc = wid & 1;
  const int l15 = lane & 15, l4 = lane >> 4;
  const int sr = lane >> 3;          // row within 8-row staging group
  const int sc = (lane & 7) * 8;     // k-element offset of this lane's 16B

  f32x4 acc[4][4];
  #pragma unroll
  for (int m = 0; m < 4; ++m)
    #pragma unroll
    for (int n = 0; n < 4; ++n) acc[m][n] = f32x4{0.f, 0.f, 0.f, 0.f};

  const int grp = wid * 4;           // 4 staging groups per wave
  for (int kt = 0; kt < K; kt += 64) {
    #pragma unroll
    for (int i = 0; i < 4; ++i) {
      const int g = grp + i;
      const int r = g * 8 + sr;
      gload16(A + (size_t)(row0 + r) * K + kt + sc, (char*)Alds + g * 1024);
      gload16(WT + (size_t)(col0 + r) * K + kt + sc, (char*)Blds + g * 1024);
    }
    __syncthreads();
    #pragma unroll
    for (int ks = 0; ks < 2; ++ks) {
      short8 a[4], b[4];
      #pragma unroll
      for (int m = 0; m < 4; ++m)
        a[m] = *(const short8*)&Alds[(wr * 64 + m * 16 + l15) * 64 + ks * 32 + l4 * 8];
      #pragma unroll
      for (int n = 0; n < 4; ++n)
        b[n] = *(const short8*)&Blds[(wc * 64 + n * 16 + l15) * 64 + ks * 32 + l4 * 8];
      #pragma unroll
      for (int m = 0; m < 4; ++m)
        #pragma unroll
        for (int n = 0; n < 4; ++n)
          acc[m][n] = mfma16x16x32_bf16(a[m], b[n], acc[m][n]);
    }
    __syncthreads();
  }

  u16* o16 = (u16*)outv;
  float* o32 = (float*)outv;
  #pragma unroll
  for (int m = 0; m < 4; ++m) {
    const int rbase = row0 + wr * 64 + m * 16 + l4 * 4;
    float fmv[4];
    if constexpr (EPI == EPI_MASK) {
      const int fl = flag[0];
      #pragma unroll
      for (int j = 0; j < 4; ++j) fmv[j] = mget(mask, fl, rbase + j) ? 1.0f : 0.0f;
    }
    #pragma unroll
    for (int n = 0; n < 4; ++n) {
      const int col = col0 + wc * 64 + n * 16 + l15;
      if (col < N) {
        const float bi = bf2f(bias[col]);
        #pragma unroll
        for (int j = 0; j < 4; ++j) {
          const size_t oi = (size_t)(rbase + j) * N + col;
          float v = acc[m][n][j] + bi;
          if constexpr (EPI == EPI_NONE) {
            o16[oi] = f2bf(v);
          } else if constexpr (EPI == EPI_MASK) {
            o16[oi] = f2bf(v * fmv[j]);
          } else if constexpr (EPI == EPI_GELU) {
            o16[oi] = f2bf(gelu_tanh(v));
          } else if constexpr (EPI == EPI_RES_TOK) {
            float r = v * 0.5f + bf2f(tok[oi]);
            o32[oi] = r;
            xmb[oi] = f2bf(r);
          } else if constexpr (EPI == EPI_RES_XM) {
            float r = v * 0.5f + xm[oi];
            if (flag[1]) o16[oi] = f2bf(r);
            else o32[oi] = r;
          }
        }
      }
    }
  }
}

// ---------------------------------------------------------------------------
// LayerNorm over rows of a [8192][384] bf16 buffer. One wave per row.
__global__ __launch_bounds__(256) void ln_kernel(const u16* __restrict__ in,
                                                 u16* __restrict__ out,
                                                 const u16* __restrict__ g,
                                                 const u16* __restrict__ bt) {
  const int row = blockIdx.x * 4 + (threadIdx.x >> 6);
  const int lane = threadIdx.x & 63;
  const u32* rp = (const u32*)(in + (size_t)row * cE);
  u32 w0 = rp[lane * 3], w1 = rp[lane * 3 + 1], w2 = rp[lane * 3 + 2];
  float x[6] = {bflo(w0), bfhi(w0), bflo(w1), bfhi(w1), bflo(w2), bfhi(w2)};
  float s = 0.f, sq = 0.f;
  #pragma unroll
  for (int j = 0; j < 6; ++j) { s += x[j]; sq += x[j] * x[j]; }
  #pragma unroll
  for (int off = 1; off < 64; off <<= 1) { s += __shfl_xor(s, off); sq += __shfl_xor(sq, off); }
  float mean = s / cE;
  float var = sq / cE - mean * mean;
  float rstd = rsqrtf(var + 1e-5f);
  u16* op = out + (size_t)row * cE;
  #pragma unroll
  for (int j = 0; j < 6; ++j) {
    int c = lane * 6 + j;
    op[c] = f2bf((x[j] - mean) * rstd * bf2f(g[c]) + bf2f(bt[c]));
  }
}

// ---------------------------------------------------------------------------
// Gathered sparse attention (unchanged from round 2).
__global__ __launch_bounds__(64) void attn_kernel(const u16* __restrict__ qkv,
                                                  const int* __restrict__ knn,
                                                  u16* __restrict__ o_out) {
  const int bq = blockIdx.x;
  const int lane = threadIdx.x;
  const int b = bq >> 12;
  __shared__ uint4 qb4[48];
  __shared__ uint4 kb4[16][48];
  __shared__ uint4 vb4[16][48];
  __shared__ int nb[16];
  __shared__ u64 sck[8][16];
  __shared__ float w[8][8];
  __shared__ int seln[8][8];
  if (lane < 16) nb[lane] = knn[bq * cKN + lane];
  if (lane < 48) qb4[lane] = *((const uint4*)(qkv + (size_t)bq * c3E) + lane);
  __syncthreads();
  for (int n = 0; n < 16; ++n) {
    const size_t rbase = ((size_t)(b * cV + nb[n])) * c3E;
    if (lane < 48) {
      kb4[n][lane] = *((const uint4*)(qkv + rbase + cE) + lane);
      vb4[n][lane] = *((const uint4*)(qkv + rbase + 2 * cE) + lane);
    }
  }
  __syncthreads();
  {
    const int h = lane >> 3;
    const int n0 = (lane & 7) * 2;
    const u32* qu = (const u32*)qb4 + h * 24;
    const u32* k0 = (const u32*)kb4 + n0 * 192 + h * 24;
    const u32* k1 = (const u32*)kb4 + (n0 + 1) * 192 + h * 24;
    float s0 = 0.f, s1 = 0.f;
    #pragma unroll
    for (int j = 0; j < 24; ++j) {
      u32 q = qu[j];
      float ql = bflo(q), qh = bfhi(q);
      u32 ka = k0[j]; s0 += ql * bflo(ka) + qh * bfhi(ka);
      u32 kb = k1[j]; s1 += ql * bflo(kb) + qh * bfhi(kb);
    }
    const float inv = 0.14433756729740643f;  // 1/sqrt(48)
    s0 *= inv; s1 *= inv;
    sck[h][n0]     = (((u64)f2ord(s0)) << 4) | (u64)(15 - n0);
    sck[h][n0 + 1] = (((u64)f2ord(s1)) << 4) | (u64)(15 - (n0 + 1));
  }
  __syncthreads();
  if ((lane & 7) == 0) {
    const int h = lane >> 3;
    float m0 = 0.f, Z = 0.f;
    #pragma unroll
    for (int r = 0; r < cTK; ++r) {
      u64 best = 0; int bn = 0;
      for (int n = 0; n < 16; ++n) { u64 kk = sck[h][n]; if (kk > best) { best = kk; bn = n; } }
      sck[h][bn] = 0;
      float sv = ord2f((u32)(best >> 4));
      seln[h][r] = 15 - (int)(best & 15ull);
      if (r == 0) m0 = sv;
      float e = expf(sv - m0);
      w[h][r] = e;
      Z += e;
    }
    float iZ = 1.0f / Z;
    #pragma unroll
    for (int r = 0; r < cTK; ++r) w[h][r] *= iZ;
  }
  __syncthreads();
  const u16* vb = (const u16*)vb4;
  #pragma unroll
  for (int rep = 0; rep < 6; ++rep) {
    int e = lane + rep * 64;
    int h = e / 48;
    float acc = 0.f;
    #pragma unroll
    for (int t = 0; t < cTK; ++t) acc += w[h][t] * bf2f(vb[seln[h][t] * cE + e]);
    o_out[(size_t)bq * cE + e] = f2bf(acc);
  }
}

// ---------------------------------------------------------------------------
extern "C" void kernel_launch(void* const* d_in, const int* in_sizes, int n_in,
                              void* d_out, int out_size, void* d_ws, size_t ws_size,
                              hipStream_t stream) {
  if (n_in < 18) return;
  const void* mask = d_in[1];

  char* ws = (char*)d_ws;
  size_t off = 0;
  auto alloc = [&](size_t bytes) { size_t o = off; off += (bytes + 255) & ~(size_t)255; return o; };
  int* flag  = (int*)(ws + alloc(256));
  int* knn   = (int*)(ws + alloc((size_t)cM * cKN * 4));
  float* XM  = (float*)(ws + alloc((size_t)cM * cD * 4));
  u16* S1    = (u16*)(ws + alloc((size_t)cM * cE * 2));
  u16* S2    = (u16*)(ws + alloc((size_t)cM * cE * 2));
  u16* QB    = (u16*)(ws + alloc((size_t)cM * c3E * 2));
  u16* HB    = QB;                                  // [8192][768] (G7 out)
  u16* S3    = QB + (size_t)cM * 2 * cE;            // [8192][384] raw / masked
  u16* XMb   = S2;                                  // bf16 copy of XM (aliased)
  u16* tokc  = (u16*)(ws + alloc((size_t)cM * cD * 2));
  u16* be    = (u16*)(ws + alloc(cE * 2));
  u16* g1    = (u16*)(ws + alloc(cE * 2));
  u16* bt1   = (u16*)(ws + alloc(cE * 2));
  u16* bqkv  = (u16*)(ws + alloc(c3E * 2));
  u16* bo    = (u16*)(ws + alloc(cE * 2));
  u16* bc    = (u16*)(ws + alloc(cD * 2));
  u16* g2    = (u16*)(ws + alloc(cE * 2));
  u16* bt2   = (u16*)(ws + alloc(cE * 2));
  u16* b1    = (u16*)(ws + alloc(2 * cE * 2));
  u16* b2    = (u16*)(ws + alloc(cE * 2));
  u16* WeT   = (u16*)(ws + alloc((size_t)384 * 192 * 2));
  u16* WqkvT = (u16*)(ws + alloc((size_t)1152 * 384 * 2));
  u16* WoT   = (u16*)(ws + alloc((size_t)384 * 384 * 2));
  u16* WcT   = (u16*)(ws + alloc((size_t)256 * 384 * 2));   // rows padded 192->256
  u16* W1T   = (u16*)(ws + alloc((size_t)768 * 384 * 2));
  u16* W2T   = (u16*)(ws + alloc((size_t)384 * 768 * 2));
  (void)ws_size; (void)in_sizes; (void)out_size;

  detect_dtype_kernel<<<1, 256, 0, stream>>>((const u32*)d_in[0], flag);
  detect_mask_kernel<<<1, 256, 0, stream>>>((const u32*)mask, flag);

  {
    ConvArgs ca;
    const int srci[11] = {0, 3, 4, 5, 7, 9, 11, 12, 13, 15, 17};
    u16* dsts[11] = {tokc, be, g1, bt1, bqkv, bo, bc, g2, bt2, b1, b2};
    const int ns[11] = {cM * cD, cE, cE, cE, c3E, cE, cD, cE, cE, 2 * cE, cE};
    for (int i = 0; i < 11; ++i) { ca.src[i] = d_in[srci[i]]; ca.dst[i] = dsts[i]; ca.n[i] = ns[i]; }
    convert_all_kernel<<<dim3(256, 11), 256, 0, stream>>>(ca, flag);
  }
  {
    TArgs ta;
    const int srci[6] = {2, 6, 8, 10, 14, 16};
    u16* dsts[6] = {WeT, WqkvT, WoT, WcT, W1T, W2T};
    const int Ks[6] = {192, 384, 384, 384, 384, 768};
    const int Ns[6] = {384, 1152, 384, 192, 768, 384};
    for (int i = 0; i < 6; ++i) { ta.src[i] = d_in[srci[i]]; ta.dst[i] = dsts[i]; ta.K[i] = Ks[i]; ta.N[i] = Ns[i]; }
    transpose_w_kernel<<<dim3(64, 6), 256, 0, stream>>>(ta, flag);
  }

  knn_kernel<<<cM, 64, 0, stream>>>(mask, flag, knn);

  const int GX = cM / 128;  // 64
  // G1: S3raw = tok @ We + be ; LN -> S1
  gemm_mfma<EPI_NONE><<<dim3(GX, 3), 256, 0, stream>>>(
      tokc, WeT, be, S3, cE, cD, nullptr, flag, nullptr, nullptr, nullptr);
  ln_kernel<<<cM / 4, 256, 0, stream>>>(S3, S1, g1, bt1);
  // G2: QB = S1 @ Wqkv + bqkv
  gemm_mfma<EPI_NONE><<<dim3(GX, 9), 256, 0, stream>>>(
      S1, WqkvT, bqkv, QB, c3E, cE, nullptr, flag, nullptr, nullptr, nullptr);
  // G3: gathered attention
  attn_kernel<<<cM, 64, 0, stream>>>(QB, knn, S2);
  // G4: S3 = (S2 @ Wo + bo) * fmask
  gemm_mfma<EPI_MASK><<<dim3(GX, 3), 256, 0, stream>>>(
      S2, WoT, bo, S3, cE, cE, mask, flag, nullptr, nullptr, nullptr);
  // G5: XM = (S3 @ Wc + bc)*0.5 + tok  (f32 + bf16 dual write)
  gemm_mfma<EPI_RES_TOK><<<dim3(GX, 2), 256, 0, stream>>>(
      S3, WcT, bc, XM, cD, cE, nullptr, flag, tokc, nullptr, XMb);
  // G6: S3raw = XMb @ We + be ; LN -> S1
  gemm_mfma<EPI_NONE><<<dim3(GX, 3), 256, 0, stream>>>(
      XMb, WeT, be, S3, cE, cD, nullptr, flag, nullptr, nullptr, nullptr);
  ln_kernel<<<cM / 4, 256, 0, stream>>>(S3, S1, g2, bt2);
  // G7: HB = gelu(S1 @ W1 + b1)
  gemm_mfma<EPI_GELU><<<dim3(GX, 6), 256, 0, stream>>>(
      S1, W1T, b1, HB, 2 * cE, cE, nullptr, flag, nullptr, nullptr, nullptr);
  // G8: S2 = HB @ W2 + b2
  gemm_mfma<EPI_NONE><<<dim3(GX, 3), 256, 0, stream>>>(
      HB, W2T, b2, S2, cE, 2 * cE, nullptr, flag, nullptr, nullptr, nullptr);
  // G9: out = (S2 @ Wc + bc)*0.5 + XM  (dtype per flag[1])
  gemm_mfma<EPI_RES_XM><<<dim3(GX, 2), 256, 0, stream>>>(
      S2, WcT, bc, d_out, cD, cE, nullptr, flag, nullptr, XM, nullptr);
}

// Round 4
// 251.895 us; speedup vs baseline: 5.1609x; 1.1571x over previous
//
#include <hip/hip_runtime.h>
#include <stdint.h>

// ============================================================================
// DSVABlockLarge — round 4: box-search KNN (exact, 9^3 + fallback), packed
// attn staging. GEMMs/LN/detect unchanged from passing round 3.
//  * KNN: per-batch 4096-bit bitmask (ballot); 4 queries/block; 9^3 box scan,
//    49-bucket histogram; exact iff 16th-smallest d2 <= 24 (outside box d2>=25);
//    else wave-parallel exact min-extraction over full grid. Tie-break
//    (d2, index) == jax.lax.top_k.
//  * attn: K/V contiguous rows staged as [16][96] uint4, 24 dense iterations.
// ============================================================================

using u16 = unsigned short;
using u32 = unsigned int;
using u64 = unsigned long long;

typedef short short8 __attribute__((ext_vector_type(8)));
typedef float f32x4 __attribute__((ext_vector_type(4)));

#define DEV static __device__ __forceinline__

constexpr int cV = 4096, cD = 192;
constexpr int cE = 384;
constexpr int cKN = 16, cTK = 8;
constexpr int cM = 2 * cV;   // 8192 rows (B*V)
constexpr int c3E = 1152;

DEV float bf2f(u16 v) { return __uint_as_float(((u32)v) << 16); }
DEV float bflo(u32 v) { return __uint_as_float(v << 16); }
DEV float bfhi(u32 v) { return __uint_as_float(v & 0xFFFF0000u); }
DEV u16 f2bf(float f) {
  u32 u = __float_as_uint(f);
  u = (u + 0x7FFFu + ((u >> 16) & 1u)) >> 16;
  return (u16)u;
}
DEV int mget(const void* mp, int flag, int i) {
  if (flag == 0) return ((const int*)mp)[i] != 0;
  if (flag == 1) return ((const float*)mp)[i] != 0.0f;
  if (flag == 2) return ((const u16*)mp)[i] != 0;
  return ((const unsigned char*)mp)[i] != 0;
}
DEV float gelu_tanh(float x) {
  float t = tanhf(0.7978845608028654f * (x + 0.044715f * x * x * x));
  return 0.5f * x * (1.0f + t);
}
DEV u32 f2ord(float f) {
  u32 u = __float_as_uint(f);
  return (u & 0x80000000u) ? ~u : (u | 0x80000000u);
}
DEV float ord2f(u32 o) {
  u32 bits = (o & 0x80000000u) ? (o & 0x7FFFFFFFu) : ~o;
  return __uint_as_float(bits);
}
DEV int bf_plausible(u32 h) {
  if (h == 0u || h == 0x8000u) return 1;
  u32 e = (h >> 7) & 0xFFu;
  return (e >= 100u && e <= 140u) ? 1 : 0;
}

using as1p = const unsigned int __attribute__((address_space(1)))*;
using as3p = unsigned int __attribute__((address_space(3)))*;
DEV void gload16(const void* g, void* l) {
  __builtin_amdgcn_global_load_lds((as1p)g, (as3p)l, 16, 0, 0);
}
DEV f32x4 mfma16x16x32_bf16(short8 a, short8 b, f32x4 c) {
  asm volatile("v_mfma_f32_16x16x32_bf16 %0, %1, %2, %0" : "+v"(c) : "v"(a), "v"(b));
  return c;
}

// ---------------------------------------------------------------------------
__global__ void detect_dtype_kernel(const u32* __restrict__ tok, int* __restrict__ flag) {
  __shared__ int cnt;
  if (threadIdx.x == 0) cnt = 0;
  __syncthreads();
  int c = 0;
  for (int i = threadIdx.x; i < 4096; i += 256) {
    u32 d = tok[i];
    c += bf_plausible(d & 0xFFFFu) & bf_plausible(d >> 16);
  }
  atomicAdd(&cnt, c);
  __syncthreads();
  if (threadIdx.x == 0) flag[1] = (cnt > 3400) ? 1 : 0;
}

__global__ void detect_mask_kernel(const u32* __restrict__ m, int* __restrict__ flag) {
  __shared__ int sa, sb, sc;
  if (threadIdx.x == 0) { sa = 0; sb = 0; sc = 0; }
  __syncthreads();
  int a = 0, b = 0, c = 0;
  for (int i = threadIdx.x; i < 2048; i += 256) {
    u32 d = m[i];
    if (!(d == 0u || d == 1u)) a = 1;
    if (!(d == 0u || d == 0x3F800000u)) b = 1;
    if (!(d == 0u || d == 0x00003F80u || d == 0x3F800000u || d == 0x3F803F80u)) c = 1;
  }
  if (a) atomicOr(&sa, 1);
  if (b) atomicOr(&sb, 1);
  if (c) atomicOr(&sc, 1);
  __syncthreads();
  if (threadIdx.x == 0) flag[0] = (sa == 0) ? 0 : ((sb == 0) ? 1 : ((sc == 0) ? 2 : 3));
}

// Per-batch 4096-bit occupancy bitmask.
__global__ __launch_bounds__(256) void build_bitmask_kernel(const void* __restrict__ mask,
                                                            const int* __restrict__ flag,
                                                            u64* __restrict__ bm) {
  const int gw = (blockIdx.x * 256 + threadIdx.x) >> 6;
  const int lane = threadIdx.x & 63;
  const int e = gw * 64 + lane;
  const int fl = flag[0];
  u64 bal = __ballot(mget(mask, fl, e) != 0);
  if (lane == 0) bm[gw] = bal;
}

// Canonicalize tok + 10 bias/gain vectors to bf16.
struct ConvArgs {
  const void* src[11];
  u16* dst[11];
  int n[11];
};
__global__ __launch_bounds__(256) void convert_all_kernel(ConvArgs a, const int* __restrict__ flag) {
  const int t = blockIdx.y;
  const int dt = flag[1];
  const int n = a.n[t];
  u16* d = a.dst[t];
  if (dt) {
    const u16* s = (const u16*)a.src[t];
    for (int i = blockIdx.x * 256 + threadIdx.x; i < n; i += gridDim.x * 256) d[i] = s[i];
  } else {
    const float* s = (const float*)a.src[t];
    for (int i = blockIdx.x * 256 + threadIdx.x; i < n; i += gridDim.x * 256) d[i] = f2bf(s[i]);
  }
}

// Transpose 6 weight matrices [K][N] -> bf16 [N][K].
struct TArgs {
  const void* src[6];
  u16* dst[6];
  int K[6];
  int N[6];
};
__global__ __launch_bounds__(256) void transpose_w_kernel(TArgs a, const int* __restrict__ flag) {
  const int t = blockIdx.y;
  const int K = a.K[t], N = a.N[t];
  const int total = K * N;
  const int dt = flag[1];
  u16* d = a.dst[t];
  for (int i = blockIdx.x * 256 + threadIdx.x; i < total; i += gridDim.x * 256) {
    int n = i / K, k = i - n * K;
    u16 vv;
    if (dt) vv = ((const u16*)a.src[t])[(size_t)k * N + n];
    else vv = f2bf(((const float*)a.src[t])[(size_t)k * N + n]);
    d[i] = vv;
  }
}

// ---------------------------------------------------------------------------
// KNN v2: 4 queries per 256-thread block; 9^3 box scan (exact iff T<=24) with
// full-grid exact min-extraction fallback.
__global__ __launch_bounds__(256) void knn_kernel(const u64* __restrict__ bitmask,
                                                  int* __restrict__ knn_out) {
  const int tid = threadIdx.x;
  const int wid = tid >> 6, lane = tid & 63;
  const int q0 = blockIdx.x * 4;
  const int b = q0 >> 12;
  const int q = q0 + wid;
  const int v = q & 4095;
  __shared__ u64 smask[64];
  __shared__ int hist4[4][64];
  __shared__ int listT[4][64];
  __shared__ int out16s[4][16];
  __shared__ int meta[4][3];
  __shared__ int cntA[4], cntT[4];
  if (tid < 64) smask[tid] = bitmask[b * 64 + tid];
  for (int i = tid; i < 4 * 64; i += 256) ((int*)hist4)[i] = 0;
  if (lane == 0) { cntA[wid] = 0; cntT[wid] = 0; }
  __syncthreads();
  const int iv = v >> 8, jv = (v >> 4) & 15, kv = v & 15;
  // pass 1: 49-bucket histogram over the 9^3 box
  #pragma unroll
  for (int t = 0; t < 12; ++t) {
    int o = t * 64 + lane;
    if (o < 729) {
      int oi = o / 81, rm = o - oi * 81;
      int oj = rm / 9, ok = rm - oj * 9;
      int i = iv + oi - 4, j = jv + oj - 4, k = kv + ok - 4;
      if (((i | j | k) & ~15) == 0) {
        int u = (i << 8) | (j << 4) | k;
        if ((smask[u >> 6] >> (u & 63)) & 1ull) {
          int di = oi - 4, dj = oj - 4, dk = ok - 4;
          atomicAdd(&hist4[wid][di * di + dj * dj + dk * dk], 1);
        }
      }
    }
  }
  __syncthreads();
  if (lane == 0) {
    int cum = 0, T = -1, below = 0;
    for (int d = 0; d <= 48; ++d) {
      int h = hist4[wid][d];
      if (h > 0 && cum + h >= cKN) { T = d; below = cum; break; }
      cum += h;
    }
    if (T > 24) T = -1;             // not provably exact -> fallback
    meta[wid][0] = T; meta[wid][1] = below; meta[wid][2] = (T < 0) ? 1 : 0;
  }
  __syncthreads();
  const int T = meta[wid][0], below = meta[wid][1], fb = meta[wid][2];
  // pass 2: collect (harmless no-op for fallback waves: T=-1 matches nothing)
  #pragma unroll
  for (int t = 0; t < 12; ++t) {
    int o = t * 64 + lane;
    if (o < 729) {
      int oi = o / 81, rm = o - oi * 81;
      int oj = rm / 9, ok = rm - oj * 9;
      int i = iv + oi - 4, j = jv + oj - 4, k = kv + ok - 4;
      if (((i | j | k) & ~15) == 0) {
        int u = (i << 8) | (j << 4) | k;
        if ((smask[u >> 6] >> (u & 63)) & 1ull) {
          int di = oi - 4, dj = oj - 4, dk = ok - 4;
          int d2 = di * di + dj * dj + dk * dk;
          if (d2 < T) { int p = atomicAdd(&cntA[wid], 1); out16s[wid][p] = u; }
          else if (d2 == T) { int p = atomicAdd(&cntT[wid], 1); if (p < 64) listT[wid][p] = u; }
        }
      }
    }
  }
  __syncthreads();
  if (!fb) {
    if (lane == 0) {
      int need = cKN - below;
      int nT = cntT[wid] < 64 ? cntT[wid] : 64;
      for (int r = 0; r < need; ++r) {
        int bi = 0, bu = 0x7FFFFFFF;
        for (int i2 = 0; i2 < nT; ++i2) { int x = listT[wid][i2]; if (x < bu) { bu = x; bi = i2; } }
        out16s[wid][below + r] = bu;
        listT[wid][bi] = 0x7FFFFFFF;
      }
    }
  } else {
    // exact full-grid fallback: 16x wave min-extraction, key (d2<<12)|u
    u64 rem = smask[lane];
    const int myi = lane >> 2;
    const int di2 = (iv - myi) * (iv - myi);
    for (int r = 0; r < cKN; ++r) {
      u64 tmp = rem;
      u32 best = 0xFFFFFFFFu;
      while (tmp) {
        int bp = __builtin_ctzll(tmp);
        tmp &= tmp - 1;
        int u = (lane << 6) | bp;
        int dj = jv - ((u >> 4) & 15), dk = kv - (u & 15);
        u32 key = (u32)(((di2 + dj * dj + dk * dk) << 12) | u);
        if (key < best) best = key;
      }
      u32 pk = (best == 0xFFFFFFFFu) ? 0xFFFFFFFFu : ((best << 6) | (u32)lane);
      #pragma unroll
      for (int off = 1; off < 64; off <<= 1) {
        u32 o2 = __shfl_xor(pk, off);
        if (o2 < pk) pk = o2;
      }
      int u = (int)((pk >> 6) & 4095u);
      int wl = (int)(pk & 63u);
      if (lane == wl) rem &= ~(1ull << (u & 63));
      if (lane == 0) out16s[wid][r] = u;
    }
  }
  __syncthreads();
  if (lane < cKN) knn_out[q * cKN + lane] = out16s[wid][lane];
}

// ---------------------------------------------------------------------------
// MFMA GEMM (unchanged from round 3).
enum { EPI_NONE = 0, EPI_MASK = 2, EPI_RES_TOK = 3, EPI_GELU = 4, EPI_RES_XM = 5 };

template <int EPI>
__global__ __launch_bounds__(256) void gemm_mfma(
    const u16* __restrict__ A, const u16* __restrict__ WT,
    const u16* __restrict__ bias, void* __restrict__ outv,
    int N, int K,
    const void* __restrict__ mask, const int* __restrict__ flag,
    const u16* __restrict__ tok, const float* __restrict__ xm,
    u16* __restrict__ xmb) {
  __shared__ alignas(16) u16 Alds[128 * 64];
  __shared__ alignas(16) u16 Blds[128 * 64];
  const int tid = threadIdx.x;
  const int lane = tid & 63;
  const int wid = tid >> 6;
  const int row0 = blockIdx.x * 128;
  const int col0 = blockIdx.y * 128;
  const int wr = wid >> 1, wc = wid & 1;
  const int l15 = lane & 15, l4 = lane >> 4;
  const int sr = lane >> 3;
  const int sc = (lane & 7) * 8;

  f32x4 acc[4][4];
  #pragma unroll
  for (int m = 0; m < 4; ++m)
    #pragma unroll
    for (int n = 0; n < 4; ++n) acc[m][n] = f32x4{0.f, 0.f, 0.f, 0.f};

  const int grp = wid * 4;
  for (int kt = 0; kt < K; kt += 64) {
    #pragma unroll
    for (int i = 0; i < 4; ++i) {
      const int g = grp + i;
      const int r = g * 8 + sr;
      gload16(A + (size_t)(row0 + r) * K + kt + sc, (char*)Alds + g * 1024);
      gload16(WT + (size_t)(col0 + r) * K + kt + sc, (char*)Blds + g * 1024);
    }
    __syncthreads();
    #pragma unroll
    for (int ks = 0; ks < 2; ++ks) {
      short8 a[4], b[4];
      #pragma unroll
      for (int m = 0; m < 4; ++m)
        a[m] = *(const short8*)&Alds[(wr * 64 + m * 16 + l15) * 64 + ks * 32 + l4 * 8];
      #pragma unroll
      for (int n = 0; n < 4; ++n)
        b[n] = *(const short8*)&Blds[(wc * 64 + n * 16 + l15) * 64 + ks * 32 + l4 * 8];
      #pragma unroll
      for (int m = 0; m < 4; ++m)
        #pragma unroll
        for (int n = 0; n < 4; ++n)
          acc[m][n] = mfma16x16x32_bf16(a[m], b[n], acc[m][n]);
    }
    __syncthreads();
  }

  u16* o16 = (u16*)outv;
  float* o32 = (float*)outv;
  #pragma unroll
  for (int m = 0; m < 4; ++m) {
    const int rbase = row0 + wr * 64 + m * 16 + l4 * 4;
    float fmv[4];
    if constexpr (EPI == EPI_MASK) {
      const int fl = flag[0];
      #pragma unroll
      for (int j = 0; j < 4; ++j) fmv[j] = mget(mask, fl, rbase + j) ? 1.0f : 0.0f;
    }
    #pragma unroll
    for (int n = 0; n < 4; ++n) {
      const int col = col0 + wc * 64 + n * 16 + l15;
      if (col < N) {
        const float bi = bf2f(bias[col]);
        #pragma unroll
        for (int j = 0; j < 4; ++j) {
          const size_t oi = (size_t)(rbase + j) * N + col;
          float v = acc[m][n][j] + bi;
          if constexpr (EPI == EPI_NONE) {
            o16[oi] = f2bf(v);
          } else if constexpr (EPI == EPI_MASK) {
            o16[oi] = f2bf(v * fmv[j]);
          } else if constexpr (EPI == EPI_GELU) {
            o16[oi] = f2bf(gelu_tanh(v));
          } else if constexpr (EPI == EPI_RES_TOK) {
            float r = v * 0.5f + bf2f(tok[oi]);
            o32[oi] = r;
            xmb[oi] = f2bf(r);
          } else if constexpr (EPI == EPI_RES_XM) {
            float r = v * 0.5f + xm[oi];
            if (flag[1]) o16[oi] = f2bf(r);
            else o32[oi] = r;
          }
        }
      }
    }
  }
}

// ---------------------------------------------------------------------------
// LayerNorm over rows of a [8192][384] bf16 buffer. One wave per row.
__global__ __launch_bounds__(256) void ln_kernel(const u16* __restrict__ in,
                                                 u16* __restrict__ out,
                                                 const u16* __restrict__ g,
                                                 const u16* __restrict__ bt) {
  const int row = blockIdx.x * 4 + (threadIdx.x >> 6);
  const int lane = threadIdx.x & 63;
  const u32* rp = (const u32*)(in + (size_t)row * cE);
  u32 w0 = rp[lane * 3], w1 = rp[lane * 3 + 1], w2 = rp[lane * 3 + 2];
  float x[6] = {bflo(w0), bfhi(w0), bflo(w1), bfhi(w1), bflo(w2), bfhi(w2)};
  float s = 0.f, sq = 0.f;
  #pragma unroll
  for (int j = 0; j < 6; ++j) { s += x[j]; sq += x[j] * x[j]; }
  #pragma unroll
  for (int off = 1; off < 64; off <<= 1) { s += __shfl_xor(s, off); sq += __shfl_xor(sq, off); }
  float mean = s / cE;
  float var = sq / cE - mean * mean;
  float rstd = rsqrtf(var + 1e-5f);
  u16* op = out + (size_t)row * cE;
  #pragma unroll
  for (int j = 0; j < 6; ++j) {
    int c = lane * 6 + j;
    op[c] = f2bf((x[j] - mean) * rstd * bf2f(g[c]) + bf2f(bt[c]));
  }
}

// ---------------------------------------------------------------------------
// Gathered sparse attention; packed [16][96]-uint4 K/V staging (K,V contiguous
// in qkv rows), all 64 lanes active, 24 dense 16B-load iterations.
__global__ __launch_bounds__(64) void attn_kernel(const u16* __restrict__ qkv,
                                                  const int* __restrict__ knn,
                                                  u16* __restrict__ o_out) {
  const int bq = blockIdx.x;
  const int lane = threadIdx.x;
  const int b = bq >> 12;
  __shared__ uint4 qb4[48];
  __shared__ uint4 kvb[16][96];   // [n][0..47]=K, [n][48..95]=V
  __shared__ int nb[16];
  __shared__ u64 sck[8][16];
  __shared__ float w[8][8];
  __shared__ int seln[8][8];
  if (lane < 16) nb[lane] = knn[bq * cKN + lane];
  if (lane < 48) qb4[lane] = *((const uint4*)(qkv + (size_t)bq * c3E) + lane);
  __syncthreads();
  #pragma unroll
  for (int t = 0; t < 24; ++t) {
    int id = t * 64 + lane;
    int n = id / 96, r = id - n * 96;
    kvb[n][r] = *((const uint4*)(qkv + ((size_t)(b * cV + nb[n])) * c3E + cE) + r);
  }
  __syncthreads();
  {
    const int h = lane >> 3;
    const int n0 = (lane & 7) * 2;
    const u32* qu = (const u32*)qb4 + h * 24;
    const u32* k0 = (const u32*)kvb + n0 * 192 + h * 24;
    const u32* k1 = (const u32*)kvb + (n0 + 1) * 192 + h * 24;
    float s0 = 0.f, s1 = 0.f;
    #pragma unroll
    for (int j = 0; j < 24; ++j) {
      u32 qv = qu[j];
      float ql = bflo(qv), qh = bfhi(qv);
      u32 ka = k0[j]; s0 += ql * bflo(ka) + qh * bfhi(ka);
      u32 kb = k1[j]; s1 += ql * bflo(kb) + qh * bfhi(kb);
    }
    const float inv = 0.14433756729740643f;  // 1/sqrt(48)
    s0 *= inv; s1 *= inv;
    sck[h][n0]     = (((u64)f2ord(s0)) << 4) | (u64)(15 - n0);
    sck[h][n0 + 1] = (((u64)f2ord(s1)) << 4) | (u64)(15 - (n0 + 1));
  }
  __syncthreads();
  if ((lane & 7) == 0) {
    const int h = lane >> 3;
    float m0 = 0.f, Z = 0.f;
    #pragma unroll
    for (int r = 0; r < cTK; ++r) {
      u64 best = 0; int bn = 0;
      for (int n = 0; n < 16; ++n) { u64 kk = sck[h][n]; if (kk > best) { best = kk; bn = n; } }
      sck[h][bn] = 0;
      float sv = ord2f((u32)(best >> 4));
      seln[h][r] = 15 - (int)(best & 15ull);
      if (r == 0) m0 = sv;
      float e = expf(sv - m0);
      w[h][r] = e;
      Z += e;
    }
    float iZ = 1.0f / Z;
    #pragma unroll
    for (int r = 0; r < cTK; ++r) w[h][r] *= iZ;
  }
  __syncthreads();
  const u16* vb = (const u16*)kvb;   // V at u16 offset n*768 + 384 + e
  #pragma unroll
  for (int rep = 0; rep < 6; ++rep) {
    int e = lane + rep * 64;
    int h = e / 48;
    float acc = 0.f;
    #pragma unroll
    for (int t = 0; t < cTK; ++t) acc += w[h][t] * bf2f(vb[seln[h][t] * 768 + 384 + e]);
    o_out[(size_t)bq * cE + e] = f2bf(acc);
  }
}

// ---------------------------------------------------------------------------
extern "C" void kernel_launch(void* const* d_in, const int* in_sizes, int n_in,
                              void* d_out, int out_size, void* d_ws, size_t ws_size,
                              hipStream_t stream) {
  if (n_in < 18) return;
  const void* mask = d_in[1];

  char* ws = (char*)d_ws;
  size_t off = 0;
  auto alloc = [&](size_t bytes) { size_t o = off; off += (bytes + 255) & ~(size_t)255; return o; };
  int* flag  = (int*)(ws + alloc(256));
  u64* bmask = (u64*)(ws + alloc(128 * 8));
  int* knn   = (int*)(ws + alloc((size_t)cM * cKN * 4));
  float* XM  = (float*)(ws + alloc((size_t)cM * cD * 4));
  u16* S1    = (u16*)(ws + alloc((size_t)cM * cE * 2));
  u16* S2    = (u16*)(ws + alloc((size_t)cM * cE * 2));
  u16* QB    = (u16*)(ws + alloc((size_t)cM * c3E * 2));
  u16* HB    = QB;                                  // [8192][768] (G7 out)
  u16* S3    = QB + (size_t)cM * 2 * cE;            // [8192][384]
  u16* XMb   = S2;                                  // bf16 copy of XM (aliased)
  u16* tokc  = (u16*)(ws + alloc((size_t)cM * cD * 2));
  u16* be    = (u16*)(ws + alloc(cE * 2));
  u16* g1    = (u16*)(ws + alloc(cE * 2));
  u16* bt1   = (u16*)(ws + alloc(cE * 2));
  u16* bqkv  = (u16*)(ws + alloc(c3E * 2));
  u16* bo    = (u16*)(ws + alloc(cE * 2));
  u16* bc    = (u16*)(ws + alloc(cD * 2));
  u16* g2    = (u16*)(ws + alloc(cE * 2));
  u16* bt2   = (u16*)(ws + alloc(cE * 2));
  u16* b1    = (u16*)(ws + alloc(2 * cE * 2));
  u16* b2    = (u16*)(ws + alloc(cE * 2));
  u16* WeT   = (u16*)(ws + alloc((size_t)384 * 192 * 2));
  u16* WqkvT = (u16*)(ws + alloc((size_t)1152 * 384 * 2));
  u16* WoT   = (u16*)(ws + alloc((size_t)384 * 384 * 2));
  u16* WcT   = (u16*)(ws + alloc((size_t)256 * 384 * 2));
  u16* W1T   = (u16*)(ws + alloc((size_t)768 * 384 * 2));
  u16* W2T   = (u16*)(ws + alloc((size_t)384 * 768 * 2));
  (void)ws_size; (void)in_sizes; (void)out_size;

  detect_dtype_kernel<<<1, 256, 0, stream>>>((const u32*)d_in[0], flag);
  detect_mask_kernel<<<1, 256, 0, stream>>>((const u32*)mask, flag);
  build_bitmask_kernel<<<32, 256, 0, stream>>>(mask, flag, bmask);

  {
    ConvArgs ca;
    const int srci[11] = {0, 3, 4, 5, 7, 9, 11, 12, 13, 15, 17};
    u16* dsts[11] = {tokc, be, g1, bt1, bqkv, bo, bc, g2, bt2, b1, b2};
    const int ns[11] = {cM * cD, cE, cE, cE, c3E, cE, cD, cE, cE, 2 * cE, cE};
    for (int i = 0; i < 11; ++i) { ca.src[i] = d_in[srci[i]]; ca.dst[i] = dsts[i]; ca.n[i] = ns[i]; }
    convert_all_kernel<<<dim3(256, 11), 256, 0, stream>>>(ca, flag);
  }
  {
    TArgs ta;
    const int srci[6] = {2, 6, 8, 10, 14, 16};
    u16* dsts[6] = {WeT, WqkvT, WoT, WcT, W1T, W2T};
    const int Ks[6] = {192, 384, 384, 384, 384, 768};
    const int Ns[6] = {384, 1152, 384, 192, 768, 384};
    for (int i = 0; i < 6; ++i) { ta.src[i] = d_in[srci[i]]; ta.dst[i] = dsts[i]; ta.K[i] = Ks[i]; ta.N[i] = Ns[i]; }
    transpose_w_kernel<<<dim3(64, 6), 256, 0, stream>>>(ta, flag);
  }

  knn_kernel<<<cM / 4, 256, 0, stream>>>(bmask, knn);

  const int GX = cM / 128;  // 64
  gemm_mfma<EPI_NONE><<<dim3(GX, 3), 256, 0, stream>>>(
      tokc, WeT, be, S3, cE, cD, nullptr, flag, nullptr, nullptr, nullptr);
  ln_kernel<<<cM / 4, 256, 0, stream>>>(S3, S1, g1, bt1);
  gemm_mfma<EPI_NONE><<<dim3(GX, 9), 256, 0, stream>>>(
      S1, WqkvT, bqkv, QB, c3E, cE, nullptr, flag, nullptr, nullptr, nullptr);
  attn_kernel<<<cM, 64, 0, stream>>>(QB, knn, S2);
  gemm_mfma<EPI_MASK><<<dim3(GX, 3), 256, 0, stream>>>(
      S2, WoT, bo, S3, cE, cE, mask, flag, nullptr, nullptr, nullptr);
  gemm_mfma<EPI_RES_TOK><<<dim3(GX, 2), 256, 0, stream>>>(
      S3, WcT, bc, XM, cD, cE, nullptr, flag, tokc, nullptr, XMb);
  gemm_mfma<EPI_NONE><<<dim3(GX, 3), 256, 0, stream>>>(
      XMb, WeT, be, S3, cE, cD, nullptr, flag, nullptr, nullptr, nullptr);
  ln_kernel<<<cM / 4, 256, 0, stream>>>(S3, S1, g2, bt2);
  gemm_mfma<EPI_GELU><<<dim3(GX, 6), 256, 0, stream>>>(
      S1, W1T, b1, HB, 2 * cE, cE, nullptr, flag, nullptr, nullptr, nullptr);
  gemm_mfma<EPI_NONE><<<dim3(GX, 3), 256, 0, stream>>>(
      HB, W2T, b2, S2, cE, 2 * cE, nullptr, flag, nullptr, nullptr, nullptr);
  gemm_mfma<EPI_RES_XM><<<dim3(GX, 2), 256, 0, stream>>>(
      S2, WcT, bc, d_out, cD, cE, nullptr, flag, nullptr, XM, nullptr);
}

// Round 5
// 227.001 us; speedup vs baseline: 5.7269x; 1.1097x over previous
//
#include <hip/hip_runtime.h>
#include <stdint.h>

// ============================================================================
// DSVABlockLarge — round 5: attn v3 (register-direct, 1-wave/query, ~1.3KB LDS,
// wave-parallel top-8). KNN/GEMM/LN/detect unchanged from passing round 4.
// ============================================================================

using u16 = unsigned short;
using u32 = unsigned int;
using u64 = unsigned long long;

typedef short short8 __attribute__((ext_vector_type(8)));
typedef float f32x4 __attribute__((ext_vector_type(4)));

#define DEV static __device__ __forceinline__

constexpr int cV = 4096, cD = 192;
constexpr int cE = 384;
constexpr int cKN = 16, cTK = 8;
constexpr int cM = 2 * cV;   // 8192 rows (B*V)
constexpr int c3E = 1152;

DEV float bf2f(u16 v) { return __uint_as_float(((u32)v) << 16); }
DEV float bflo(u32 v) { return __uint_as_float(v << 16); }
DEV float bfhi(u32 v) { return __uint_as_float(v & 0xFFFF0000u); }
DEV u16 f2bf(float f) {
  u32 u = __float_as_uint(f);
  u = (u + 0x7FFFu + ((u >> 16) & 1u)) >> 16;
  return (u16)u;
}
DEV int mget(const void* mp, int flag, int i) {
  if (flag == 0) return ((const int*)mp)[i] != 0;
  if (flag == 1) return ((const float*)mp)[i] != 0.0f;
  if (flag == 2) return ((const u16*)mp)[i] != 0;
  return ((const unsigned char*)mp)[i] != 0;
}
DEV float gelu_tanh(float x) {
  float t = tanhf(0.7978845608028654f * (x + 0.044715f * x * x * x));
  return 0.5f * x * (1.0f + t);
}
DEV u32 f2ord(float f) {
  u32 u = __float_as_uint(f);
  return (u & 0x80000000u) ? ~u : (u | 0x80000000u);
}
DEV float ord2f(u32 o) {
  u32 bits = (o & 0x80000000u) ? (o & 0x7FFFFFFFu) : ~o;
  return __uint_as_float(bits);
}
DEV int bf_plausible(u32 h) {
  if (h == 0u || h == 0x8000u) return 1;
  u32 e = (h >> 7) & 0xFFu;
  return (e >= 100u && e <= 140u) ? 1 : 0;
}

using as1p = const unsigned int __attribute__((address_space(1)))*;
using as3p = unsigned int __attribute__((address_space(3)))*;
DEV void gload16(const void* g, void* l) {
  __builtin_amdgcn_global_load_lds((as1p)g, (as3p)l, 16, 0, 0);
}
DEV f32x4 mfma16x16x32_bf16(short8 a, short8 b, f32x4 c) {
  asm volatile("v_mfma_f32_16x16x32_bf16 %0, %1, %2, %0" : "+v"(c) : "v"(a), "v"(b));
  return c;
}

// ---------------------------------------------------------------------------
__global__ void detect_dtype_kernel(const u32* __restrict__ tok, int* __restrict__ flag) {
  __shared__ int cnt;
  if (threadIdx.x == 0) cnt = 0;
  __syncthreads();
  int c = 0;
  for (int i = threadIdx.x; i < 4096; i += 256) {
    u32 d = tok[i];
    c += bf_plausible(d & 0xFFFFu) & bf_plausible(d >> 16);
  }
  atomicAdd(&cnt, c);
  __syncthreads();
  if (threadIdx.x == 0) flag[1] = (cnt > 3400) ? 1 : 0;
}

__global__ void detect_mask_kernel(const u32* __restrict__ m, int* __restrict__ flag) {
  __shared__ int sa, sb, sc;
  if (threadIdx.x == 0) { sa = 0; sb = 0; sc = 0; }
  __syncthreads();
  int a = 0, b = 0, c = 0;
  for (int i = threadIdx.x; i < 2048; i += 256) {
    u32 d = m[i];
    if (!(d == 0u || d == 1u)) a = 1;
    if (!(d == 0u || d == 0x3F800000u)) b = 1;
    if (!(d == 0u || d == 0x00003F80u || d == 0x3F800000u || d == 0x3F803F80u)) c = 1;
  }
  if (a) atomicOr(&sa, 1);
  if (b) atomicOr(&sb, 1);
  if (c) atomicOr(&sc, 1);
  __syncthreads();
  if (threadIdx.x == 0) flag[0] = (sa == 0) ? 0 : ((sb == 0) ? 1 : ((sc == 0) ? 2 : 3));
}

// Per-batch 4096-bit occupancy bitmask.
__global__ __launch_bounds__(256) void build_bitmask_kernel(const void* __restrict__ mask,
                                                            const int* __restrict__ flag,
                                                            u64* __restrict__ bm) {
  const int gw = (blockIdx.x * 256 + threadIdx.x) >> 6;
  const int lane = threadIdx.x & 63;
  const int e = gw * 64 + lane;
  const int fl = flag[0];
  u64 bal = __ballot(mget(mask, fl, e) != 0);
  if (lane == 0) bm[gw] = bal;
}

// Canonicalize tok + 10 bias/gain vectors to bf16.
struct ConvArgs {
  const void* src[11];
  u16* dst[11];
  int n[11];
};
__global__ __launch_bounds__(256) void convert_all_kernel(ConvArgs a, const int* __restrict__ flag) {
  const int t = blockIdx.y;
  const int dt = flag[1];
  const int n = a.n[t];
  u16* d = a.dst[t];
  if (dt) {
    const u16* s = (const u16*)a.src[t];
    for (int i = blockIdx.x * 256 + threadIdx.x; i < n; i += gridDim.x * 256) d[i] = s[i];
  } else {
    const float* s = (const float*)a.src[t];
    for (int i = blockIdx.x * 256 + threadIdx.x; i < n; i += gridDim.x * 256) d[i] = f2bf(s[i]);
  }
}

// Transpose 6 weight matrices [K][N] -> bf16 [N][K].
struct TArgs {
  const void* src[6];
  u16* dst[6];
  int K[6];
  int N[6];
};
__global__ __launch_bounds__(256) void transpose_w_kernel(TArgs a, const int* __restrict__ flag) {
  const int t = blockIdx.y;
  const int K = a.K[t], N = a.N[t];
  const int total = K * N;
  const int dt = flag[1];
  u16* d = a.dst[t];
  for (int i = blockIdx.x * 256 + threadIdx.x; i < total; i += gridDim.x * 256) {
    int n = i / K, k = i - n * K;
    u16 vv;
    if (dt) vv = ((const u16*)a.src[t])[(size_t)k * N + n];
    else vv = f2bf(((const float*)a.src[t])[(size_t)k * N + n]);
    d[i] = vv;
  }
}

// ---------------------------------------------------------------------------
// KNN v2 (unchanged from round 4): 9^3 box scan exact iff T<=24, fallback.
__global__ __launch_bounds__(256) void knn_kernel(const u64* __restrict__ bitmask,
                                                  int* __restrict__ knn_out) {
  const int tid = threadIdx.x;
  const int wid = tid >> 6, lane = tid & 63;
  const int q0 = blockIdx.x * 4;
  const int b = q0 >> 12;
  const int q = q0 + wid;
  const int v = q & 4095;
  __shared__ u64 smask[64];
  __shared__ int hist4[4][64];
  __shared__ int listT[4][64];
  __shared__ int out16s[4][16];
  __shared__ int meta[4][3];
  __shared__ int cntA[4], cntT[4];
  if (tid < 64) smask[tid] = bitmask[b * 64 + tid];
  for (int i = tid; i < 4 * 64; i += 256) ((int*)hist4)[i] = 0;
  if (lane == 0) { cntA[wid] = 0; cntT[wid] = 0; }
  __syncthreads();
  const int iv = v >> 8, jv = (v >> 4) & 15, kv = v & 15;
  #pragma unroll
  for (int t = 0; t < 12; ++t) {
    int o = t * 64 + lane;
    if (o < 729) {
      int oi = o / 81, rm = o - oi * 81;
      int oj = rm / 9, ok = rm - oj * 9;
      int i = iv + oi - 4, j = jv + oj - 4, k = kv + ok - 4;
      if (((i | j | k) & ~15) == 0) {
        int u = (i << 8) | (j << 4) | k;
        if ((smask[u >> 6] >> (u & 63)) & 1ull) {
          int di = oi - 4, dj = oj - 4, dk = ok - 4;
          atomicAdd(&hist4[wid][di * di + dj * dj + dk * dk], 1);
        }
      }
    }
  }
  __syncthreads();
  if (lane == 0) {
    int cum = 0, T = -1, below = 0;
    for (int d = 0; d <= 48; ++d) {
      int h = hist4[wid][d];
      if (h > 0 && cum + h >= cKN) { T = d; below = cum; break; }
      cum += h;
    }
    if (T > 24) T = -1;
    meta[wid][0] = T; meta[wid][1] = below; meta[wid][2] = (T < 0) ? 1 : 0;
  }
  __syncthreads();
  const int T = meta[wid][0], below = meta[wid][1], fb = meta[wid][2];
  #pragma unroll
  for (int t = 0; t < 12; ++t) {
    int o = t * 64 + lane;
    if (o < 729) {
      int oi = o / 81, rm = o - oi * 81;
      int oj = rm / 9, ok = rm - oj * 9;
      int i = iv + oi - 4, j = jv + oj - 4, k = kv + ok - 4;
      if (((i | j | k) & ~15) == 0) {
        int u = (i << 8) | (j << 4) | k;
        if ((smask[u >> 6] >> (u & 63)) & 1ull) {
          int di = oi - 4, dj = oj - 4, dk = ok - 4;
          int d2 = di * di + dj * dj + dk * dk;
          if (d2 < T) { int p = atomicAdd(&cntA[wid], 1); out16s[wid][p] = u; }
          else if (d2 == T) { int p = atomicAdd(&cntT[wid], 1); if (p < 64) listT[wid][p] = u; }
        }
      }
    }
  }
  __syncthreads();
  if (!fb) {
    if (lane == 0) {
      int need = cKN - below;
      int nT = cntT[wid] < 64 ? cntT[wid] : 64;
      for (int r = 0; r < need; ++r) {
        int bi = 0, bu = 0x7FFFFFFF;
        for (int i2 = 0; i2 < nT; ++i2) { int x = listT[wid][i2]; if (x < bu) { bu = x; bi = i2; } }
        out16s[wid][below + r] = bu;
        listT[wid][bi] = 0x7FFFFFFF;
      }
    }
  } else {
    u64 rem = smask[lane];
    const int myi = lane >> 2;
    const int di2 = (iv - myi) * (iv - myi);
    for (int r = 0; r < cKN; ++r) {
      u64 tmp = rem;
      u32 best = 0xFFFFFFFFu;
      while (tmp) {
        int bp = __builtin_ctzll(tmp);
        tmp &= tmp - 1;
        int u = (lane << 6) | bp;
        int dj = jv - ((u >> 4) & 15), dk = kv - (u & 15);
        u32 key = (u32)(((di2 + dj * dj + dk * dk) << 12) | u);
        if (key < best) best = key;
      }
      u32 pk = (best == 0xFFFFFFFFu) ? 0xFFFFFFFFu : ((best << 6) | (u32)lane);
      #pragma unroll
      for (int off = 1; off < 64; off <<= 1) {
        u32 o2 = __shfl_xor(pk, off);
        if (o2 < pk) pk = o2;
      }
      int u = (int)((pk >> 6) & 4095u);
      int wl = (int)(pk & 63u);
      if (lane == wl) rem &= ~(1ull << (u & 63));
      if (lane == 0) out16s[wid][r] = u;
    }
  }
  __syncthreads();
  if (lane < cKN) knn_out[q * cKN + lane] = out16s[wid][lane];
}

// ---------------------------------------------------------------------------
// MFMA GEMM (unchanged from round 3/4).
enum { EPI_NONE = 0, EPI_MASK = 2, EPI_RES_TOK = 3, EPI_GELU = 4, EPI_RES_XM = 5 };

template <int EPI>
__global__ __launch_bounds__(256) void gemm_mfma(
    const u16* __restrict__ A, const u16* __restrict__ WT,
    const u16* __restrict__ bias, void* __restrict__ outv,
    int N, int K,
    const void* __restrict__ mask, const int* __restrict__ flag,
    const u16* __restrict__ tok, const float* __restrict__ xm,
    u16* __restrict__ xmb) {
  __shared__ alignas(16) u16 Alds[128 * 64];
  __shared__ alignas(16) u16 Blds[128 * 64];
  const int tid = threadIdx.x;
  const int lane = tid & 63;
  const int wid = tid >> 6;
  const int row0 = blockIdx.x * 128;
  const int col0 = blockIdx.y * 128;
  const int wr = wid >> 1, wc = wid & 1;
  const int l15 = lane & 15, l4 = lane >> 4;
  const int sr = lane >> 3;
  const int sc = (lane & 7) * 8;

  f32x4 acc[4][4];
  #pragma unroll
  for (int m = 0; m < 4; ++m)
    #pragma unroll
    for (int n = 0; n < 4; ++n) acc[m][n] = f32x4{0.f, 0.f, 0.f, 0.f};

  const int grp = wid * 4;
  for (int kt = 0; kt < K; kt += 64) {
    #pragma unroll
    for (int i = 0; i < 4; ++i) {
      const int g = grp + i;
      const int r = g * 8 + sr;
      gload16(A + (size_t)(row0 + r) * K + kt + sc, (char*)Alds + g * 1024);
      gload16(WT + (size_t)(col0 + r) * K + kt + sc, (char*)Blds + g * 1024);
    }
    __syncthreads();
    #pragma unroll
    for (int ks = 0; ks < 2; ++ks) {
      short8 a[4], b[4];
      #pragma unroll
      for (int m = 0; m < 4; ++m)
        a[m] = *(const short8*)&Alds[(wr * 64 + m * 16 + l15) * 64 + ks * 32 + l4 * 8];
      #pragma unroll
      for (int n = 0; n < 4; ++n)
        b[n] = *(const short8*)&Blds[(wc * 64 + n * 16 + l15) * 64 + ks * 32 + l4 * 8];
      #pragma unroll
      for (int m = 0; m < 4; ++m)
        #pragma unroll
        for (int n = 0; n < 4; ++n)
          acc[m][n] = mfma16x16x32_bf16(a[m], b[n], acc[m][n]);
    }
    __syncthreads();
  }

  u16* o16 = (u16*)outv;
  float* o32 = (float*)outv;
  #pragma unroll
  for (int m = 0; m < 4; ++m) {
    const int rbase = row0 + wr * 64 + m * 16 + l4 * 4;
    float fmv[4];
    if constexpr (EPI == EPI_MASK) {
      const int fl = flag[0];
      #pragma unroll
      for (int j = 0; j < 4; ++j) fmv[j] = mget(mask, fl, rbase + j) ? 1.0f : 0.0f;
    }
    #pragma unroll
    for (int n = 0; n < 4; ++n) {
      const int col = col0 + wc * 64 + n * 16 + l15;
      if (col < N) {
        const float bi = bf2f(bias[col]);
        #pragma unroll
        for (int j = 0; j < 4; ++j) {
          const size_t oi = (size_t)(rbase + j) * N + col;
          float v = acc[m][n][j] + bi;
          if constexpr (EPI == EPI_NONE) {
            o16[oi] = f2bf(v);
          } else if constexpr (EPI == EPI_MASK) {
            o16[oi] = f2bf(v * fmv[j]);
          } else if constexpr (EPI == EPI_GELU) {
            o16[oi] = f2bf(gelu_tanh(v));
          } else if constexpr (EPI == EPI_RES_TOK) {
            float r = v * 0.5f + bf2f(tok[oi]);
            o32[oi] = r;
            xmb[oi] = f2bf(r);
          } else if constexpr (EPI == EPI_RES_XM) {
            float r = v * 0.5f + xm[oi];
            if (flag[1]) o16[oi] = f2bf(r);
            else o32[oi] = r;
          }
        }
      }
    }
  }
}

// ---------------------------------------------------------------------------
// LayerNorm over rows of a [8192][384] bf16 buffer. One wave per row.
__global__ __launch_bounds__(256) void ln_kernel(const u16* __restrict__ in,
                                                 u16* __restrict__ out,
                                                 const u16* __restrict__ g,
                                                 const u16* __restrict__ bt) {
  const int row = blockIdx.x * 4 + (threadIdx.x >> 6);
  const int lane = threadIdx.x & 63;
  const u32* rp = (const u32*)(in + (size_t)row * cE);
  u32 w0 = rp[lane * 3], w1 = rp[lane * 3 + 1], w2 = rp[lane * 3 + 2];
  float x[6] = {bflo(w0), bfhi(w0), bflo(w1), bfhi(w1), bflo(w2), bfhi(w2)};
  float s = 0.f, sq = 0.f;
  #pragma unroll
  for (int j = 0; j < 6; ++j) { s += x[j]; sq += x[j] * x[j]; }
  #pragma unroll
  for (int off = 1; off < 64; off <<= 1) { s += __shfl_xor(s, off); sq += __shfl_xor(sq, off); }
  float mean = s / cE;
  float var = sq / cE - mean * mean;
  float rstd = rsqrtf(var + 1e-5f);
  u16* op = out + (size_t)row * cE;
  #pragma unroll
  for (int j = 0; j < 6; ++j) {
    int c = lane * 6 + j;
    op[c] = f2bf((x[j] - mean) * rstd * bf2f(g[c]) + bf2f(bt[c]));
  }
}

// ---------------------------------------------------------------------------
// attn v3: 4 queries per 256-thread block, one wave per query, ~1.4KB LDS.
// Score phase register-direct from global (L2-resident qkv); wave-parallel
// top-8 via 8-lane-group shfl_xor max on (ord(score)<<4 | 15-n) keys (exact
// jax.lax.top_k tie-break); V gathered post-selection, coalesced.
__global__ __launch_bounds__(256) void attn_kernel(const u16* __restrict__ qkv,
                                                   const int* __restrict__ knn,
                                                   u16* __restrict__ o_out) {
  const int wid = threadIdx.x >> 6;
  const int lane = threadIdx.x & 63;
  const int bq = blockIdx.x * 4 + wid;
  const int b = bq >> 12;
  __shared__ float w4[4][8][8];
  __shared__ int vid4[4][8][8];
  __shared__ int nb4[4][16];
  float (*w)[8] = w4[wid];
  int (*vid)[8] = vid4[wid];
  int* nb = nb4[wid];
  if (lane < 16) nb[lane] = knn[bq * cKN + lane];
  const int h = lane >> 3;
  const int j = lane & 7;
  // q segment for head h (redundant across the 8 group lanes; L1-served)
  const uint2* qp = (const uint2*)(qkv + (size_t)bq * c3E + h * 48);
  const int r0 = nb[j], r1 = nb[j + 8];   // LDS read (same-wave ordering)
  const uint2* k0p = (const uint2*)(qkv + ((size_t)(b * cV + r0)) * c3E + cE + h * 48);
  const uint2* k1p = (const uint2*)(qkv + ((size_t)(b * cV + r1)) * c3E + cE + h * 48);
  float s0 = 0.f, s1 = 0.f;
  #pragma unroll
  for (int t = 0; t < 12; ++t) {
    uint2 qv = qp[t];
    uint2 k0 = k0p[t];
    uint2 k1 = k1p[t];
    s0 += bflo(qv.x) * bflo(k0.x) + bfhi(qv.x) * bfhi(k0.x)
        + bflo(qv.y) * bflo(k0.y) + bfhi(qv.y) * bfhi(k0.y);
    s1 += bflo(qv.x) * bflo(k1.x) + bfhi(qv.x) * bfhi(k1.x)
        + bflo(qv.y) * bflo(k1.y) + bfhi(qv.y) * bfhi(k1.y);
  }
  const float inv = 0.14433756729740643f;  // 1/sqrt(48)
  u64 key0 = (((u64)f2ord(s0 * inv)) << 4) | (u64)(15 - j);
  u64 key1 = (((u64)f2ord(s1 * inv)) << 4) | (u64)(15 - (j + 8));
  float m0 = 0.f, Z = 0.f, myw = 0.f;
  int myv = 0;
  #pragma unroll
  for (int r = 0; r < cTK; ++r) {
    u64 best = key0 > key1 ? key0 : key1;
    u64 o1 = __shfl_xor(best, 1); if (o1 > best) best = o1;
    u64 o2 = __shfl_xor(best, 2); if (o2 > best) best = o2;
    u64 o4 = __shfl_xor(best, 4); if (o4 > best) best = o4;
    if (key0 == best) key0 = 0;
    if (key1 == best) key1 = 0;
    float sv = ord2f((u32)(best >> 4));
    int nsel = 15 - (int)(best & 15ull);
    if (r == 0) m0 = sv;
    float e = expf(sv - m0);
    Z += e;
    if (j == r) { myw = e; myv = nsel; }
  }
  w[h][j] = myw / Z;        // all group lanes hold identical Z
  vid[h][j] = nb[myv];
  // PV: gather 8 selected V rows, coalesced across lanes.
  const u16* vbase = qkv + (size_t)(b * cV) * c3E + 2 * cE;
  #pragma unroll
  for (int rep = 0; rep < 6; ++rep) {
    int e = rep * 64 + lane;
    int h2 = e / 48;
    float acc = 0.f;
    #pragma unroll
    for (int t = 0; t < cTK; ++t)
      acc += w[h2][t] * bf2f(vbase[(size_t)vid[h2][t] * c3E + e]);
    o_out[(size_t)bq * cE + e] = f2bf(acc);
  }
}

// ---------------------------------------------------------------------------
extern "C" void kernel_launch(void* const* d_in, const int* in_sizes, int n_in,
                              void* d_out, int out_size, void* d_ws, size_t ws_size,
                              hipStream_t stream) {
  if (n_in < 18) return;
  const void* mask = d_in[1];

  char* ws = (char*)d_ws;
  size_t off = 0;
  auto alloc = [&](size_t bytes) { size_t o = off; off += (bytes + 255) & ~(size_t)255; return o; };
  int* flag  = (int*)(ws + alloc(256));
  u64* bmask = (u64*)(ws + alloc(128 * 8));
  int* knn   = (int*)(ws + alloc((size_t)cM * cKN * 4));
  float* XM  = (float*)(ws + alloc((size_t)cM * cD * 4));
  u16* S1    = (u16*)(ws + alloc((size_t)cM * cE * 2));
  u16* S2    = (u16*)(ws + alloc((size_t)cM * cE * 2));
  u16* QB    = (u16*)(ws + alloc((size_t)cM * c3E * 2));
  u16* HB    = QB;
  u16* S3    = QB + (size_t)cM * 2 * cE;
  u16* XMb   = S2;
  u16* tokc  = (u16*)(ws + alloc((size_t)cM * cD * 2));
  u16* be    = (u16*)(ws + alloc(cE * 2));
  u16* g1    = (u16*)(ws + alloc(cE * 2));
  u16* bt1   = (u16*)(ws + alloc(cE * 2));
  u16* bqkv  = (u16*)(ws + alloc(c3E * 2));
  u16* bo    = (u16*)(ws + alloc(cE * 2));
  u16* bc    = (u16*)(ws + alloc(cD * 2));
  u16* g2    = (u16*)(ws + alloc(cE * 2));
  u16* bt2   = (u16*)(ws + alloc(cE * 2));
  u16* b1    = (u16*)(ws + alloc(2 * cE * 2));
  u16* b2    = (u16*)(ws + alloc(cE * 2));
  u16* WeT   = (u16*)(ws + alloc((size_t)384 * 192 * 2));
  u16* WqkvT = (u16*)(ws + alloc((size_t)1152 * 384 * 2));
  u16* WoT   = (u16*)(ws + alloc((size_t)384 * 384 * 2));
  u16* WcT   = (u16*)(ws + alloc((size_t)256 * 384 * 2));
  u16* W1T   = (u16*)(ws + alloc((size_t)768 * 384 * 2));
  u16* W2T   = (u16*)(ws + alloc((size_t)384 * 768 * 2));
  (void)ws_size; (void)in_sizes; (void)out_size;

  detect_dtype_kernel<<<1, 256, 0, stream>>>((const u32*)d_in[0], flag);
  detect_mask_kernel<<<1, 256, 0, stream>>>((const u32*)mask, flag);
  build_bitmask_kernel<<<32, 256, 0, stream>>>(mask, flag, bmask);

  {
    ConvArgs ca;
    const int srci[11] = {0, 3, 4, 5, 7, 9, 11, 12, 13, 15, 17};
    u16* dsts[11] = {tokc, be, g1, bt1, bqkv, bo, bc, g2, bt2, b1, b2};
    const int ns[11] = {cM * cD, cE, cE, cE, c3E, cE, cD, cE, cE, 2 * cE, cE};
    for (int i = 0; i < 11; ++i) { ca.src[i] = d_in[srci[i]]; ca.dst[i] = dsts[i]; ca.n[i] = ns[i]; }
    convert_all_kernel<<<dim3(256, 11), 256, 0, stream>>>(ca, flag);
  }
  {
    TArgs ta;
    const int srci[6] = {2, 6, 8, 10, 14, 16};
    u16* dsts[6] = {WeT, WqkvT, WoT, WcT, W1T, W2T};
    const int Ks[6] = {192, 384, 384, 384, 384, 768};
    const int Ns[6] = {384, 1152, 384, 192, 768, 384};
    for (int i = 0; i < 6; ++i) { ta.src[i] = d_in[srci[i]]; ta.dst[i] = dsts[i]; ta.K[i] = Ks[i]; ta.N[i] = Ns[i]; }
    transpose_w_kernel<<<dim3(64, 6), 256, 0, stream>>>(ta, flag);
  }

  knn_kernel<<<cM / 4, 256, 0, stream>>>(bmask, knn);

  const int GX = cM / 128;  // 64
  gemm_mfma<EPI_NONE><<<dim3(GX, 3), 256, 0, stream>>>(
      tokc, WeT, be, S3, cE, cD, nullptr, flag, nullptr, nullptr, nullptr);
  ln_kernel<<<cM / 4, 256, 0, stream>>>(S3, S1, g1, bt1);
  gemm_mfma<EPI_NONE><<<dim3(GX, 9), 256, 0, stream>>>(
      S1, WqkvT, bqkv, QB, c3E, cE, nullptr, flag, nullptr, nullptr, nullptr);
  attn_kernel<<<cM / 4, 256, 0, stream>>>(QB, knn, S2);
  gemm_mfma<EPI_MASK><<<dim3(GX, 3), 256, 0, stream>>>(
      S2, WoT, bo, S3, cE, cE, mask, flag, nullptr, nullptr, nullptr);
  gemm_mfma<EPI_RES_TOK><<<dim3(GX, 2), 256, 0, stream>>>(
      S3, WcT, bc, XM, cD, cE, nullptr, flag, tokc, nullptr, XMb);
  gemm_mfma<EPI_NONE><<<dim3(GX, 3), 256, 0, stream>>>(
      XMb, WeT, be, S3, cE, cD, nullptr, flag, nullptr, nullptr, nullptr);
  ln_kernel<<<cM / 4, 256, 0, stream>>>(S3, S1, g2, bt2);
  gemm_mfma<EPI_GELU><<<dim3(GX, 6), 256, 0, stream>>>(
      S1, W1T, b1, HB, 2 * cE, cE, nullptr, flag, nullptr, nullptr, nullptr);
  gemm_mfma<EPI_NONE><<<dim3(GX, 3), 256, 0, stream>>>(
      HB, W2T, b2, S2, cE, 2 * cE, nullptr, flag, nullptr, nullptr, nullptr);
  gemm_mfma<EPI_RES_XM><<<dim3(GX, 2), 256, 0, stream>>>(
      S2, WcT, bc, d_out, cD, cE, nullptr, flag, nullptr, XM, nullptr);
}

// Round 6
// 201.451 us; speedup vs baseline: 6.4532x; 1.1268x over previous
//
#include <hip/hip_runtime.h>
#include <stdint.h>

// ============================================================================
// DSVABlockLarge — round 6: fewer dispatches + better GEMM grids.
//  * G1/G6 fused GEMM+LayerNorm (BM=64, full N=384 staged, 8 waves, in-block
//    row stats via shfl + LDS). LN on f32 pre-rounding accumulators.
//  * Other GEMMs: BM=64 x BN=128 tile (24KB LDS) -> all grids >= 256 blocks.
//  * Setup: 1 detect kernel + 1 prep kernel (convert/transpose/bitmask jobs).
//  * KNN / attn unchanged from passing round 5.
// ============================================================================

using u16 = unsigned short;
using u32 = unsigned int;
using u64 = unsigned long long;

typedef short short8 __attribute__((ext_vector_type(8)));
typedef float f32x4 __attribute__((ext_vector_type(4)));

#define DEV static __device__ __forceinline__

constexpr int cV = 4096, cD = 192;
constexpr int cE = 384;
constexpr int cKN = 16, cTK = 8;
constexpr int cM = 2 * cV;   // 8192 rows (B*V)
constexpr int c3E = 1152;

DEV float bf2f(u16 v) { return __uint_as_float(((u32)v) << 16); }
DEV float bflo(u32 v) { return __uint_as_float(v << 16); }
DEV float bfhi(u32 v) { return __uint_as_float(v & 0xFFFF0000u); }
DEV u16 f2bf(float f) {
  u32 u = __float_as_uint(f);
  u = (u + 0x7FFFu + ((u >> 16) & 1u)) >> 16;
  return (u16)u;
}
DEV int mget(const void* mp, int flag, int i) {
  if (flag == 0) return ((const int*)mp)[i] != 0;
  if (flag == 1) return ((const float*)mp)[i] != 0.0f;
  if (flag == 2) return ((const u16*)mp)[i] != 0;
  return ((const unsigned char*)mp)[i] != 0;
}
DEV float gelu_tanh(float x) {
  float t = tanhf(0.7978845608028654f * (x + 0.044715f * x * x * x));
  return 0.5f * x * (1.0f + t);
}
DEV u32 f2ord(float f) {
  u32 u = __float_as_uint(f);
  return (u & 0x80000000u) ? ~u : (u | 0x80000000u);
}
DEV float ord2f(u32 o) {
  u32 bits = (o & 0x80000000u) ? (o & 0x7FFFFFFFu) : ~o;
  return __uint_as_float(bits);
}
DEV int bf_plausible(u32 h) {
  if (h == 0u || h == 0x8000u) return 1;
  u32 e = (h >> 7) & 0xFFu;
  return (e >= 100u && e <= 140u) ? 1 : 0;
}

using as1p = const unsigned int __attribute__((address_space(1)))*;
using as3p = unsigned int __attribute__((address_space(3)))*;
DEV void gload16(const void* g, void* l) {
  __builtin_amdgcn_global_load_lds((as1p)g, (as3p)l, 16, 0, 0);
}
DEV f32x4 mfma16x16x32_bf16(short8 a, short8 b, f32x4 c) {
  asm volatile("v_mfma_f32_16x16x32_bf16 %0, %1, %2, %0" : "+v"(c) : "v"(a), "v"(b));
  return c;
}

// ---------------------------------------------------------------------------
// Combined dtype + mask-encoding detection. flag[0]=mask enc, flag[1]=bf16?
__global__ void detect_all_kernel(const u32* __restrict__ tok,
                                  const u32* __restrict__ m,
                                  int* __restrict__ flag) {
  __shared__ int cnt, sa, sb, sc;
  if (threadIdx.x == 0) { cnt = 0; sa = 0; sb = 0; sc = 0; }
  __syncthreads();
  int c = 0;
  for (int i = threadIdx.x; i < 4096; i += 256) {
    u32 d = tok[i];
    c += bf_plausible(d & 0xFFFFu) & bf_plausible(d >> 16);
  }
  atomicAdd(&cnt, c);
  int a = 0, b = 0, cc = 0;
  for (int i = threadIdx.x; i < 2048; i += 256) {
    u32 d = m[i];
    if (!(d == 0u || d == 1u)) a = 1;
    if (!(d == 0u || d == 0x3F800000u)) b = 1;
    if (!(d == 0u || d == 0x00003F80u || d == 0x3F800000u || d == 0x3F803F80u)) cc = 1;
  }
  if (a) atomicOr(&sa, 1);
  if (b) atomicOr(&sb, 1);
  if (cc) atomicOr(&sc, 1);
  __syncthreads();
  if (threadIdx.x == 0) {
    flag[1] = (cnt > 3400) ? 1 : 0;
    flag[0] = (sa == 0) ? 0 : ((sb == 0) ? 1 : ((sc == 0) ? 2 : 3));
  }
}

// ---------------------------------------------------------------------------
// Prep kernel: y-jobs 0..10 convert-to-bf16, 11..16 transpose, 17 bitmask.
struct PrepArgs {
  const void* csrc[11]; u16* cdst[11]; int cn[11];
  const void* tsrc[6]; u16* tdst[6]; int tK[6]; int tN[6];
  const void* mask; u64* bm;
};
__global__ __launch_bounds__(256) void prep_kernel(PrepArgs a, const int* __restrict__ flag) {
  const int job = blockIdx.y;
  const int dt = flag[1];
  if (job < 11) {
    const int n = a.cn[job];
    u16* d = a.cdst[job];
    if (dt) {
      const u16* s = (const u16*)a.csrc[job];
      for (int i = blockIdx.x * 256 + threadIdx.x; i < n; i += gridDim.x * 256) d[i] = s[i];
    } else {
      const float* s = (const float*)a.csrc[job];
      for (int i = blockIdx.x * 256 + threadIdx.x; i < n; i += gridDim.x * 256) d[i] = f2bf(s[i]);
    }
  } else if (job < 17) {
    const int t = job - 11;
    const int K = a.tK[t], N = a.tN[t];
    const int total = K * N;
    u16* d = a.tdst[t];
    for (int i = blockIdx.x * 256 + threadIdx.x; i < total; i += gridDim.x * 256) {
      int n = i / K, k = i - n * K;
      u16 vv;
      if (dt) vv = ((const u16*)a.tsrc[t])[(size_t)k * N + n];
      else vv = f2bf(((const float*)a.tsrc[t])[(size_t)k * N + n]);
      d[i] = vv;
    }
  } else {
    const int gw = (blockIdx.x * 256 + threadIdx.x) >> 6;
    const int lane = threadIdx.x & 63;
    if (gw < 128) {
      const int fl = flag[0];
      u64 bal = __ballot(mget(a.mask, fl, gw * 64 + lane) != 0);
      if (lane == 0) a.bm[gw] = bal;
    }
  }
}

// ---------------------------------------------------------------------------
// KNN v2 (unchanged from rounds 4/5).
__global__ __launch_bounds__(256) void knn_kernel(const u64* __restrict__ bitmask,
                                                  int* __restrict__ knn_out) {
  const int tid = threadIdx.x;
  const int wid = tid >> 6, lane = tid & 63;
  const int q0 = blockIdx.x * 4;
  const int b = q0 >> 12;
  const int q = q0 + wid;
  const int v = q & 4095;
  __shared__ u64 smask[64];
  __shared__ int hist4[4][64];
  __shared__ int listT[4][64];
  __shared__ int out16s[4][16];
  __shared__ int meta[4][3];
  __shared__ int cntA[4], cntT[4];
  if (tid < 64) smask[tid] = bitmask[b * 64 + tid];
  for (int i = tid; i < 4 * 64; i += 256) ((int*)hist4)[i] = 0;
  if (lane == 0) { cntA[wid] = 0; cntT[wid] = 0; }
  __syncthreads();
  const int iv = v >> 8, jv = (v >> 4) & 15, kv = v & 15;
  #pragma unroll
  for (int t = 0; t < 12; ++t) {
    int o = t * 64 + lane;
    if (o < 729) {
      int oi = o / 81, rm = o - oi * 81;
      int oj = rm / 9, ok = rm - oj * 9;
      int i = iv + oi - 4, j = jv + oj - 4, k = kv + ok - 4;
      if (((i | j | k) & ~15) == 0) {
        int u = (i << 8) | (j << 4) | k;
        if ((smask[u >> 6] >> (u & 63)) & 1ull) {
          int di = oi - 4, dj = oj - 4, dk = ok - 4;
          atomicAdd(&hist4[wid][di * di + dj * dj + dk * dk], 1);
        }
      }
    }
  }
  __syncthreads();
  if (lane == 0) {
    int cum = 0, T = -1, below = 0;
    for (int d = 0; d <= 48; ++d) {
      int h = hist4[wid][d];
      if (h > 0 && cum + h >= cKN) { T = d; below = cum; break; }
      cum += h;
    }
    if (T > 24) T = -1;
    meta[wid][0] = T; meta[wid][1] = below; meta[wid][2] = (T < 0) ? 1 : 0;
  }
  __syncthreads();
  const int T = meta[wid][0], below = meta[wid][1], fb = meta[wid][2];
  #pragma unroll
  for (int t = 0; t < 12; ++t) {
    int o = t * 64 + lane;
    if (o < 729) {
      int oi = o / 81, rm = o - oi * 81;
      int oj = rm / 9, ok = rm - oj * 9;
      int i = iv + oi - 4, j = jv + oj - 4, k = kv + ok - 4;
      if (((i | j | k) & ~15) == 0) {
        int u = (i << 8) | (j << 4) | k;
        if ((smask[u >> 6] >> (u & 63)) & 1ull) {
          int di = oi - 4, dj = oj - 4, dk = ok - 4;
          int d2 = di * di + dj * dj + dk * dk;
          if (d2 < T) { int p = atomicAdd(&cntA[wid], 1); out16s[wid][p] = u; }
          else if (d2 == T) { int p = atomicAdd(&cntT[wid], 1); if (p < 64) listT[wid][p] = u; }
        }
      }
    }
  }
  __syncthreads();
  if (!fb) {
    if (lane == 0) {
      int need = cKN - below;
      int nT = cntT[wid] < 64 ? cntT[wid] : 64;
      for (int r = 0; r < need; ++r) {
        int bi = 0, bu = 0x7FFFFFFF;
        for (int i2 = 0; i2 < nT; ++i2) { int x = listT[wid][i2]; if (x < bu) { bu = x; bi = i2; } }
        out16s[wid][below + r] = bu;
        listT[wid][bi] = 0x7FFFFFFF;
      }
    }
  } else {
    u64 rem = smask[lane];
    const int myi = lane >> 2;
    const int di2 = (iv - myi) * (iv - myi);
    for (int r = 0; r < cKN; ++r) {
      u64 tmp = rem;
      u32 best = 0xFFFFFFFFu;
      while (tmp) {
        int bp = __builtin_ctzll(tmp);
        tmp &= tmp - 1;
        int u = (lane << 6) | bp;
        int dj = jv - ((u >> 4) & 15), dk = kv - (u & 15);
        u32 key = (u32)(((di2 + dj * dj + dk * dk) << 12) | u);
        if (key < best) best = key;
      }
      u32 pk = (best == 0xFFFFFFFFu) ? 0xFFFFFFFFu : ((best << 6) | (u32)lane);
      #pragma unroll
      for (int off = 1; off < 64; off <<= 1) {
        u32 o2 = __shfl_xor(pk, off);
        if (o2 < pk) pk = o2;
      }
      int u = (int)((pk >> 6) & 4095u);
      int wl = (int)(pk & 63u);
      if (lane == wl) rem &= ~(1ull << (u & 63));
      if (lane == 0) out16s[wid][r] = u;
    }
  }
  __syncthreads();
  if (lane < cKN) knn_out[q * cKN + lane] = out16s[wid][lane];
}

// ---------------------------------------------------------------------------
// Fused GEMM + LayerNorm: S1 = LN(A[8192,K] @ WeT^T + be; g, bt).
// BM=64, BN=384 (full width), BK=64, 8 waves (512 thr) as 4(M) x 2(N).
__global__ __launch_bounds__(512) void gemm_ln(
    const u16* __restrict__ A, const u16* __restrict__ WT,
    const u16* __restrict__ bias, const u16* __restrict__ g,
    const u16* __restrict__ bt, u16* __restrict__ out, int K) {
  __shared__ alignas(16) u16 Alds[64 * 64];
  __shared__ alignas(16) u16 Blds[384 * 64];
  __shared__ float st[64][2][2];
  const int tid = threadIdx.x;
  const int lane = tid & 63;
  const int wave = tid >> 6;
  const int wrow = wave >> 1, wcol = wave & 1;
  const int l15 = lane & 15, l4 = lane >> 4;
  const int sr = lane >> 3;
  const int sc = (lane & 7) * 8;
  const int row0 = blockIdx.x * 64;

  f32x4 acc[12];
  #pragma unroll
  for (int n = 0; n < 12; ++n) acc[n] = f32x4{0.f, 0.f, 0.f, 0.f};

  for (int kt = 0; kt < K; kt += 64) {
    #pragma unroll
    for (int i = 0; i < 7; ++i) {
      const int gidx = wave * 7 + i;
      const int r = (gidx & 7) * 8 + sr;   // row within its 64-row span
      if (gidx < 8) {
        gload16(A + (size_t)(row0 + gidx * 8 + sr) * K + kt + sc, (char*)Alds + gidx * 1024);
      } else {
        const int rb = (gidx - 8) * 8 + sr;   // 0..383
        gload16(WT + (size_t)rb * K + kt + sc, (char*)Blds + (gidx - 8) * 1024);
      }
      (void)r;
    }
    __syncthreads();
    #pragma unroll
    for (int ks = 0; ks < 2; ++ks) {
      short8 a = *(const short8*)&Alds[(wrow * 16 + l15) * 64 + ks * 32 + l4 * 8];
      #pragma unroll
      for (int n = 0; n < 12; ++n) {
        short8 b = *(const short8*)&Blds[(wcol * 192 + n * 16 + l15) * 64 + ks * 32 + l4 * 8];
        acc[n] = mfma16x16x32_bf16(a, b, acc[n]);
      }
    }
    __syncthreads();
  }

  // bias + row stats (this wave covers cols wcol*192 .. +191 of rows wrow*16..+15)
  #pragma unroll
  for (int n = 0; n < 12; ++n) {
    const float bi = bf2f(bias[wcol * 192 + n * 16 + l15]);
    #pragma unroll
    for (int j = 0; j < 4; ++j) acc[n][j] += bi;
  }
  float s[4] = {0, 0, 0, 0}, sq[4] = {0, 0, 0, 0};
  #pragma unroll
  for (int n = 0; n < 12; ++n)
    #pragma unroll
    for (int j = 0; j < 4; ++j) { s[j] += acc[n][j]; sq[j] += acc[n][j] * acc[n][j]; }
  #pragma unroll
  for (int off = 1; off < 16; off <<= 1) {
    #pragma unroll
    for (int j = 0; j < 4; ++j) { s[j] += __shfl_xor(s[j], off); sq[j] += __shfl_xor(sq[j], off); }
  }
  if (l15 == 0) {
    #pragma unroll
    for (int j = 0; j < 4; ++j) {
      const int r = wrow * 16 + l4 * 4 + j;
      st[r][wcol][0] = s[j];
      st[r][wcol][1] = sq[j];
    }
  }
  __syncthreads();
  const float invN = 1.0f / 384.0f;
  #pragma unroll
  for (int j = 0; j < 4; ++j) {
    const int rl = wrow * 16 + l4 * 4 + j;
    const float mean = (st[rl][0][0] + st[rl][1][0]) * invN;
    const float var = (st[rl][0][1] + st[rl][1][1]) * invN - mean * mean;
    const float rstd = rsqrtf(var + 1e-5f);
    const size_t obase = (size_t)(row0 + rl) * cE;
    #pragma unroll
    for (int n = 0; n < 12; ++n) {
      const int col = wcol * 192 + n * 16 + l15;
      out[obase + col] = f2bf((acc[n][j] - mean) * rstd * bf2f(g[col]) + bf2f(bt[col]));
    }
  }
}

// ---------------------------------------------------------------------------
// General MFMA GEMM: BM=64 x BN=128, BK=64, 4 waves as 2(M) x 2(N).
enum { EPI_NONE = 0, EPI_MASK = 2, EPI_RES_TOK = 3, EPI_GELU = 4, EPI_RES_XM = 5 };

template <int EPI>
__global__ __launch_bounds__(256) void gemm_mfma(
    const u16* __restrict__ A, const u16* __restrict__ WT,
    const u16* __restrict__ bias, void* __restrict__ outv,
    int N, int K,
    const void* __restrict__ mask, const int* __restrict__ flag,
    const u16* __restrict__ tok, const float* __restrict__ xm,
    u16* __restrict__ xmb) {
  __shared__ alignas(16) u16 Alds[64 * 64];
  __shared__ alignas(16) u16 Blds[128 * 64];
  const int tid = threadIdx.x;
  const int lane = tid & 63;
  const int wave = tid >> 6;
  const int wrow = wave >> 1, wcol = wave & 1;
  const int l15 = lane & 15, l4 = lane >> 4;
  const int sr = lane >> 3;
  const int sc = (lane & 7) * 8;
  const int row0 = blockIdx.x * 64;
  const int col0 = blockIdx.y * 128;

  f32x4 acc[2][4];
  #pragma unroll
  for (int m = 0; m < 2; ++m)
    #pragma unroll
    for (int n = 0; n < 4; ++n) acc[m][n] = f32x4{0.f, 0.f, 0.f, 0.f};

  for (int kt = 0; kt < K; kt += 64) {
    #pragma unroll
    for (int i = 0; i < 6; ++i) {
      const int gidx = wave * 6 + i;
      if (gidx < 8) {
        gload16(A + (size_t)(row0 + gidx * 8 + sr) * K + kt + sc, (char*)Alds + gidx * 1024);
      } else {
        const int rb = (gidx - 8) * 8 + sr;   // 0..127
        gload16(WT + (size_t)(col0 + rb) * K + kt + sc, (char*)Blds + (gidx - 8) * 1024);
      }
    }
    __syncthreads();
    #pragma unroll
    for (int ks = 0; ks < 2; ++ks) {
      short8 a[2], b[4];
      #pragma unroll
      for (int m = 0; m < 2; ++m)
        a[m] = *(const short8*)&Alds[(wrow * 32 + m * 16 + l15) * 64 + ks * 32 + l4 * 8];
      #pragma unroll
      for (int n = 0; n < 4; ++n)
        b[n] = *(const short8*)&Blds[(wcol * 64 + n * 16 + l15) * 64 + ks * 32 + l4 * 8];
      #pragma unroll
      for (int m = 0; m < 2; ++m)
        #pragma unroll
        for (int n = 0; n < 4; ++n)
          acc[m][n] = mfma16x16x32_bf16(a[m], b[n], acc[m][n]);
    }
    __syncthreads();
  }

  u16* o16 = (u16*)outv;
  float* o32 = (float*)outv;
  #pragma unroll
  for (int m = 0; m < 2; ++m) {
    const int rbase = row0 + wrow * 32 + m * 16 + l4 * 4;
    float fmv[4];
    if constexpr (EPI == EPI_MASK) {
      const int fl = flag[0];
      #pragma unroll
      for (int j = 0; j < 4; ++j) fmv[j] = mget(mask, fl, rbase + j) ? 1.0f : 0.0f;
    }
    #pragma unroll
    for (int n = 0; n < 4; ++n) {
      const int col = col0 + wcol * 64 + n * 16 + l15;
      if (col < N) {
        const float bi = bf2f(bias[col]);
        #pragma unroll
        for (int j = 0; j < 4; ++j) {
          const size_t oi = (size_t)(rbase + j) * N + col;
          float v = acc[m][n][j] + bi;
          if constexpr (EPI == EPI_NONE) {
            o16[oi] = f2bf(v);
          } else if constexpr (EPI == EPI_MASK) {
            o16[oi] = f2bf(v * fmv[j]);
          } else if constexpr (EPI == EPI_GELU) {
            o16[oi] = f2bf(gelu_tanh(v));
          } else if constexpr (EPI == EPI_RES_TOK) {
            float r = v * 0.5f + bf2f(tok[oi]);
            o32[oi] = r;
            xmb[oi] = f2bf(r);
          } else if constexpr (EPI == EPI_RES_XM) {
            float r = v * 0.5f + xm[oi];
            if (flag[1]) o16[oi] = f2bf(r);
            else o32[oi] = r;
          }
        }
      }
    }
  }
}

// ---------------------------------------------------------------------------
// attn v3 (unchanged from round 5).
__global__ __launch_bounds__(256) void attn_kernel(const u16* __restrict__ qkv,
                                                   const int* __restrict__ knn,
                                                   u16* __restrict__ o_out) {
  const int wid = threadIdx.x >> 6;
  const int lane = threadIdx.x & 63;
  const int bq = blockIdx.x * 4 + wid;
  const int b = bq >> 12;
  __shared__ float w4[4][8][8];
  __shared__ int vid4[4][8][8];
  __shared__ int nb4[4][16];
  float (*w)[8] = w4[wid];
  int (*vid)[8] = vid4[wid];
  int* nb = nb4[wid];
  if (lane < 16) nb[lane] = knn[bq * cKN + lane];
  const int h = lane >> 3;
  const int j = lane & 7;
  const uint2* qp = (const uint2*)(qkv + (size_t)bq * c3E + h * 48);
  const int r0 = nb[j], r1 = nb[j + 8];
  const uint2* k0p = (const uint2*)(qkv + ((size_t)(b * cV + r0)) * c3E + cE + h * 48);
  const uint2* k1p = (const uint2*)(qkv + ((size_t)(b * cV + r1)) * c3E + cE + h * 48);
  float s0 = 0.f, s1 = 0.f;
  #pragma unroll
  for (int t = 0; t < 12; ++t) {
    uint2 qv = qp[t];
    uint2 k0 = k0p[t];
    uint2 k1 = k1p[t];
    s0 += bflo(qv.x) * bflo(k0.x) + bfhi(qv.x) * bfhi(k0.x)
        + bflo(qv.y) * bflo(k0.y) + bfhi(qv.y) * bfhi(k0.y);
    s1 += bflo(qv.x) * bflo(k1.x) + bfhi(qv.x) * bfhi(k1.x)
        + bflo(qv.y) * bflo(k1.y) + bfhi(qv.y) * bfhi(k1.y);
  }
  const float inv = 0.14433756729740643f;  // 1/sqrt(48)
  u64 key0 = (((u64)f2ord(s0 * inv)) << 4) | (u64)(15 - j);
  u64 key1 = (((u64)f2ord(s1 * inv)) << 4) | (u64)(15 - (j + 8));
  float m0 = 0.f, Z = 0.f, myw = 0.f;
  int myv = 0;
  #pragma unroll
  for (int r = 0; r < cTK; ++r) {
    u64 best = key0 > key1 ? key0 : key1;
    u64 o1 = __shfl_xor(best, 1); if (o1 > best) best = o1;
    u64 o2 = __shfl_xor(best, 2); if (o2 > best) best = o2;
    u64 o4 = __shfl_xor(best, 4); if (o4 > best) best = o4;
    if (key0 == best) key0 = 0;
    if (key1 == best) key1 = 0;
    float sv = ord2f((u32)(best >> 4));
    int nsel = 15 - (int)(best & 15ull);
    if (r == 0) m0 = sv;
    float e = expf(sv - m0);
    Z += e;
    if (j == r) { myw = e; myv = nsel; }
  }
  w[h][j] = myw / Z;
  vid[h][j] = nb[myv];
  const u16* vbase = qkv + (size_t)(b * cV) * c3E + 2 * cE;
  #pragma unroll
  for (int rep = 0; rep < 6; ++rep) {
    int e = rep * 64 + lane;
    int h2 = e / 48;
    float acc = 0.f;
    #pragma unroll
    for (int t = 0; t < cTK; ++t)
      acc += w[h2][t] * bf2f(vbase[(size_t)vid[h2][t] * c3E + e]);
    o_out[(size_t)bq * cE + e] = f2bf(acc);
  }
}

// ---------------------------------------------------------------------------
extern "C" void kernel_launch(void* const* d_in, const int* in_sizes, int n_in,
                              void* d_out, int out_size, void* d_ws, size_t ws_size,
                              hipStream_t stream) {
  if (n_in < 18) return;
  const void* mask = d_in[1];

  char* ws = (char*)d_ws;
  size_t off = 0;
  auto alloc = [&](size_t bytes) { size_t o = off; off += (bytes + 255) & ~(size_t)255; return o; };
  int* flag  = (int*)(ws + alloc(256));
  u64* bmask = (u64*)(ws + alloc(128 * 8));
  int* knn   = (int*)(ws + alloc((size_t)cM * cKN * 4));
  float* XM  = (float*)(ws + alloc((size_t)cM * cD * 4));
  u16* S1    = (u16*)(ws + alloc((size_t)cM * cE * 2));
  u16* S2    = (u16*)(ws + alloc((size_t)cM * cE * 2));
  u16* QB    = (u16*)(ws + alloc((size_t)cM * c3E * 2));
  u16* HB    = QB;                         // [8192][768] reuse (G7 out)
  u16* S3    = QB + (size_t)cM * 2 * cE;   // [8192][384]
  u16* XMb   = S2;                         // bf16 copy of XM (aliased)
  u16* tokc  = (u16*)(ws + alloc((size_t)cM * cD * 2));
  u16* be    = (u16*)(ws + alloc(cE * 2));
  u16* g1    = (u16*)(ws + alloc(cE * 2));
  u16* bt1   = (u16*)(ws + alloc(cE * 2));
  u16* bqkv  = (u16*)(ws + alloc(c3E * 2));
  u16* bo    = (u16*)(ws + alloc(cE * 2));
  u16* bc    = (u16*)(ws + alloc(cD * 2));
  u16* g2    = (u16*)(ws + alloc(cE * 2));
  u16* bt2   = (u16*)(ws + alloc(cE * 2));
  u16* b1    = (u16*)(ws + alloc(2 * cE * 2));
  u16* b2    = (u16*)(ws + alloc(cE * 2));
  u16* WeT   = (u16*)(ws + alloc((size_t)384 * 192 * 2));
  u16* WqkvT = (u16*)(ws + alloc((size_t)1152 * 384 * 2));
  u16* WoT   = (u16*)(ws + alloc((size_t)384 * 384 * 2));
  u16* WcT   = (u16*)(ws + alloc((size_t)256 * 384 * 2));   // rows padded 192->256
  u16* W1T   = (u16*)(ws + alloc((size_t)768 * 384 * 2));
  u16* W2T   = (u16*)(ws + alloc((size_t)384 * 768 * 2));
  (void)ws_size; (void)in_sizes; (void)out_size;

  detect_all_kernel<<<1, 256, 0, stream>>>((const u32*)d_in[0], (const u32*)mask, flag);

  {
    PrepArgs pa;
    const int csrci[11] = {0, 3, 4, 5, 7, 9, 11, 12, 13, 15, 17};
    u16* cdsts[11] = {tokc, be, g1, bt1, bqkv, bo, bc, g2, bt2, b1, b2};
    const int cns[11] = {cM * cD, cE, cE, cE, c3E, cE, cD, cE, cE, 2 * cE, cE};
    for (int i = 0; i < 11; ++i) { pa.csrc[i] = d_in[csrci[i]]; pa.cdst[i] = cdsts[i]; pa.cn[i] = cns[i]; }
    const int tsrci[6] = {2, 6, 8, 10, 14, 16};
    u16* tdsts[6] = {WeT, WqkvT, WoT, WcT, W1T, W2T};
    const int tKs[6] = {192, 384, 384, 384, 384, 768};
    const int tNs[6] = {384, 1152, 384, 192, 768, 384};
    for (int i = 0; i < 6; ++i) { pa.tsrc[i] = d_in[tsrci[i]]; pa.tdst[i] = tdsts[i]; pa.tK[i] = tKs[i]; pa.tN[i] = tNs[i]; }
    pa.mask = mask; pa.bm = bmask;
    prep_kernel<<<dim3(96, 18), 256, 0, stream>>>(pa, flag);
  }

  knn_kernel<<<cM / 4, 256, 0, stream>>>(bmask, knn);

  const int GR = cM / 64;  // 128 row-blocks
  // G1+LN: S1 = LN(tok @ We + be; g1,bt1)
  gemm_ln<<<GR, 512, 0, stream>>>(tokc, WeT, be, g1, bt1, S1, cD);
  // G2: QB = S1 @ Wqkv + bqkv
  gemm_mfma<EPI_NONE><<<dim3(GR, 9), 256, 0, stream>>>(
      S1, WqkvT, bqkv, QB, c3E, cE, nullptr, flag, nullptr, nullptr, nullptr);
  // G3: gathered attention
  attn_kernel<<<cM / 4, 256, 0, stream>>>(QB, knn, S2);
  // G4: S3 = (S2 @ Wo + bo) * fmask
  gemm_mfma<EPI_MASK><<<dim3(GR, 3), 256, 0, stream>>>(
      S2, WoT, bo, S3, cE, cE, mask, flag, nullptr, nullptr, nullptr);
  // G5: XM = (S3 @ Wc + bc)*0.5 + tok  (f32 + bf16 dual write)
  gemm_mfma<EPI_RES_TOK><<<dim3(GR, 2), 256, 0, stream>>>(
      S3, WcT, bc, XM, cD, cE, nullptr, flag, tokc, nullptr, XMb);
  // G6+LN: S1 = LN(XMb @ We + be; g2,bt2)
  gemm_ln<<<GR, 512, 0, stream>>>(XMb, WeT, be, g2, bt2, S1, cD);
  // G7: HB = gelu(S1 @ W1 + b1)
  gemm_mfma<EPI_GELU><<<dim3(GR, 6), 256, 0, stream>>>(
      S1, W1T, b1, HB, 2 * cE, cE, nullptr, flag, nullptr, nullptr, nullptr);
  // G8: S2 = HB @ W2 + b2
  gemm_mfma<EPI_NONE><<<dim3(GR, 3), 256, 0, stream>>>(
      HB, W2T, b2, S2, cE, 2 * cE, nullptr, flag, nullptr, nullptr, nullptr);
  // G9: out = (S2 @ Wc + bc)*0.5 + XM  (dtype per flag[1])
  gemm_mfma<EPI_RES_XM><<<dim3(GR, 2), 256, 0, stream>>>(
      S2, WcT, bc, d_out, cD, cE, nullptr, flag, nullptr, XM, nullptr);
}